// Round 1
// baseline (754.560 us; speedup 1.0000x reference)
//
#include <hip/hip_runtime.h>

#define ND 25000
#define NG 20000
#define NE 1000000
#define NTOT (ND + NG)      // 45000
#define NSCAN_BLOCKS 44     // ceil(45000/1024)

// ---- workspace layout (bytes), all 256B-aligned ----
#define OFF_CNT   0ull            // NTOT int   (180000 B)  -- zeroed
#define OFF_CUR   180000ull       // NTOT int   (180000 B)  -- zeroed (contiguous with CNT)
#define OFF_ROW   360448ull       // NTOT+1 int
#define OFF_BSUM  540672ull       // 64 int
#define OFF_COL   541184ull       // 2*NE int (8,000,000 B)
#define OFF_MEANG 8541184ull      // NG*128 f32 (10,240,000 B)
#define OFF_MEAND 18781184ull     // ND*128 f32 (12,800,000 B)
#define OFF_G1    31581184ull     // NG*128 f32
#define OFF_D1    41821184ull     // ND*128 f32
// total ~54.6 MB

// ---------------- degree count (combined: [0,ND) = src/disease, [ND,NTOT) = dst/gene) -------------
__global__ __launch_bounds__(256) void count_deg(const int* __restrict__ src,
                                                 const int* __restrict__ dst,
                                                 int* __restrict__ cnt, int E) {
    int e = blockIdx.x * 256 + threadIdx.x;
    if (e < E) {
        atomicAdd(&cnt[src[e]], 1);
        atomicAdd(&cnt[ND + dst[e]], 1);
    }
}

// ---------------- scan pass 1: per-block (1024 elems) exclusive scan + block sums -----------------
__global__ __launch_bounds__(256) void scan1(const int* __restrict__ cnt,
                                             int* __restrict__ row,
                                             int* __restrict__ bsum, int N) {
    __shared__ int sd[256];
    int t = threadIdx.x;
    int base = blockIdx.x * 1024 + t * 4;
    int v[4];
#pragma unroll
    for (int j = 0; j < 4; ++j) {
        int idx = base + j;
        v[j] = (idx < N) ? cnt[idx] : 0;
    }
    int tsum = v[0] + v[1] + v[2] + v[3];
    sd[t] = tsum;
    __syncthreads();
    for (int off = 1; off < 256; off <<= 1) {
        int x = (t >= off) ? sd[t - off] : 0;
        __syncthreads();
        sd[t] += x;
        __syncthreads();
    }
    int run = sd[t] - tsum;   // exclusive prefix of this thread
#pragma unroll
    for (int j = 0; j < 4; ++j) {
        int idx = base + j;
        if (idx < N) row[idx] = run;
        run += v[j];
    }
    if (t == 255) bsum[blockIdx.x] = sd[255];
}

// ---------------- scan pass 2: add block offsets, write row[N] ------------------------------------
__global__ __launch_bounds__(256) void scan2(int* __restrict__ row,
                                             const int* __restrict__ bsum,
                                             int N, int total) {
    int off = 0;
    for (int b2 = 0; b2 < (int)blockIdx.x; ++b2) off += bsum[b2];  // uniform -> scalar loads
    int t = threadIdx.x;
    int base = blockIdx.x * 1024 + t * 4;
#pragma unroll
    for (int j = 0; j < 4; ++j) {
        int idx = base + j;
        if (idx < N) row[idx] += off;
    }
    if (blockIdx.x == 0 && t == 0) row[N] = total;
}

// ---------------- CSR fill ------------------------------------------------------------------------
__global__ __launch_bounds__(256) void fill_csr(const int* __restrict__ src,
                                                const int* __restrict__ dst,
                                                const int* __restrict__ row,
                                                int* __restrict__ cur,
                                                int* __restrict__ col, int E) {
    int e = blockIdx.x * 256 + threadIdx.x;
    if (e < E) {
        int s = src[e], d = dst[e];
        int p = row[s] + atomicAdd(&cur[s], 1);
        col[p] = d;                                  // disease row: gene neighbors
        int q = row[ND + d] + atomicAdd(&cur[ND + d], 1);
        col[q] = s;                                  // gene row: disease neighbors
    }
}

// ---------------- per-node mean aggregation: one wave per node, float2 per lane -------------------
__global__ __launch_bounds__(256) void agg_mean(const float* __restrict__ X,
                                                const int* __restrict__ rowptr,
                                                const int* __restrict__ col,
                                                float* __restrict__ out, int n) {
    int wid = threadIdx.x >> 6;
    int lane = threadIdx.x & 63;
    int node = blockIdx.x * 4 + wid;
    if (node >= n) return;
    int b = rowptr[node], e = rowptr[node + 1];
    const float2* xp = (const float2*)X;
    float sx = 0.f, sy = 0.f;
    int j = b;
    for (; j + 4 <= e; j += 4) {
        int c0 = col[j], c1 = col[j + 1], c2 = col[j + 2], c3 = col[j + 3];
        float2 v0 = xp[(size_t)c0 * 64 + lane];
        float2 v1 = xp[(size_t)c1 * 64 + lane];
        float2 v2 = xp[(size_t)c2 * 64 + lane];
        float2 v3 = xp[(size_t)c3 * 64 + lane];
        sx += (v0.x + v1.x) + (v2.x + v3.x);
        sy += (v0.y + v1.y) + (v2.y + v3.y);
    }
    for (; j < e; ++j) {
        int c = col[j];
        float2 v = xp[(size_t)c * 64 + lane];
        sx += v.x;
        sy += v.y;
    }
    int deg = e - b;
    float r = 1.0f / (float)(deg > 0 ? deg : 1);
    float2 o;
    o.x = sx * r;
    o.y = sy * r;
    ((float2*)out)[(size_t)node * 64 + lane] = o;
}

// ---------------- dual GEMM: Y = A1@W1 + A2@W2 + b  (rows of 128, weights 128x128 row-major) ------
// block = 256 threads, 32 rows per block; A tiles transposed in LDS (broadcast reads);
// each thread computes a 4-node x 4-feature micro-tile.
__global__ __launch_bounds__(256) void gemm_dual(const float* __restrict__ A1,
                                                 const float* __restrict__ A2,
                                                 const float* __restrict__ W1,
                                                 const float* __restrict__ W2,
                                                 const float* __restrict__ bias,
                                                 float* __restrict__ Y, int n) {
    __shared__ __align__(16) float aT1[128 * 32];
    __shared__ __align__(16) float aT2[128 * 32];
    int t = threadIdx.x;
    int n0 = blockIdx.x * 32;

    // stage A1/A2 tile transposed: aT[k][node_local]
    {
        int nl = t & 31;     // node 0..31
        int kc = t >> 5;     // 0..7, 16 k each
        int node = n0 + nl;
        bool ok = node < n;
        const float4* a1p = (const float4*)(A1 + (size_t)(ok ? node : 0) * 128);
        const float4* a2p = (const float4*)(A2 + (size_t)(ok ? node : 0) * 128);
#pragma unroll
        for (int q = 0; q < 4; ++q) {
            int k = kc * 16 + q * 4;
            float4 v1 = ok ? a1p[k >> 2] : make_float4(0.f, 0.f, 0.f, 0.f);
            float4 v2 = ok ? a2p[k >> 2] : make_float4(0.f, 0.f, 0.f, 0.f);
            aT1[(k + 0) * 32 + nl] = v1.x;
            aT1[(k + 1) * 32 + nl] = v1.y;
            aT1[(k + 2) * 32 + nl] = v1.z;
            aT1[(k + 3) * 32 + nl] = v1.w;
            aT2[(k + 0) * 32 + nl] = v2.x;
            aT2[(k + 1) * 32 + nl] = v2.y;
            aT2[(k + 2) * 32 + nl] = v2.z;
            aT2[(k + 3) * 32 + nl] = v2.w;
        }
    }
    __syncthreads();

    int fg = t & 31;        // feature quad: features 4fg..4fg+3
    int ng = t >> 5;        // node quad: local nodes 4ng..4ng+3
    int ng4 = ng * 4;
    float acc[4][4];
#pragma unroll
    for (int i = 0; i < 4; ++i)
#pragma unroll
        for (int j = 0; j < 4; ++j) acc[i][j] = 0.f;

    const float4* Wp1 = (const float4*)W1 + fg;
    const float4* Wp2 = (const float4*)W2 + fg;

#pragma unroll 4
    for (int k = 0; k < 128; ++k) {
        float4 w1 = Wp1[k * 32];
        float4 w2 = Wp2[k * 32];
        float4 a1 = *(const float4*)&aT1[k * 32 + ng4];
        float4 a2 = *(const float4*)&aT2[k * 32 + ng4];
        float av1[4] = {a1.x, a1.y, a1.z, a1.w};
        float av2[4] = {a2.x, a2.y, a2.z, a2.w};
        float wv1[4] = {w1.x, w1.y, w1.z, w1.w};
        float wv2[4] = {w2.x, w2.y, w2.z, w2.w};
#pragma unroll
        for (int i = 0; i < 4; ++i)
#pragma unroll
            for (int j = 0; j < 4; ++j)
                acc[i][j] += av1[i] * wv1[j] + av2[i] * wv2[j];
    }

    float4 bb = ((const float4*)bias)[fg];
#pragma unroll
    for (int i = 0; i < 4; ++i) {
        int node = n0 + ng4 + i;
        if (node < n) {
            float4 o;
            o.x = acc[i][0] + bb.x;
            o.y = acc[i][1] + bb.y;
            o.z = acc[i][2] + bb.z;
            o.w = acc[i][3] + bb.w;
            *(float4*)(Y + (size_t)node * 128 + fg * 4) = o;
        }
    }
}

extern "C" void kernel_launch(void* const* d_in, const int* in_sizes, int n_in,
                              void* d_out, int out_size, void* d_ws, size_t ws_size,
                              hipStream_t stream) {
    const float* x_d     = (const float*)d_in[0];
    const float* x_g     = (const float*)d_in[1];
    const int*   src     = (const int*)d_in[2];
    const int*   dst     = (const int*)d_in[3];
    const float* w1_dg_l = (const float*)d_in[4];
    const float* b1_dg   = (const float*)d_in[5];
    const float* w1_dg_r = (const float*)d_in[6];
    const float* w1_gd_l = (const float*)d_in[7];
    const float* b1_gd   = (const float*)d_in[8];
    const float* w1_gd_r = (const float*)d_in[9];
    const float* w2_dg_l = (const float*)d_in[10];
    const float* b2_dg   = (const float*)d_in[11];
    const float* w2_dg_r = (const float*)d_in[12];
    const float* w2_gd_l = (const float*)d_in[13];
    const float* b2_gd   = (const float*)d_in[14];
    const float* w2_gd_r = (const float*)d_in[15];
    float* out = (float*)d_out;

    char* ws = (char*)d_ws;
    int*   cnt    = (int*)(ws + OFF_CNT);
    int*   cur    = (int*)(ws + OFF_CUR);
    int*   row    = (int*)(ws + OFF_ROW);
    int*   bsum   = (int*)(ws + OFF_BSUM);
    int*   col    = (int*)(ws + OFF_COL);
    float* mean_g = (float*)(ws + OFF_MEANG);
    float* mean_d = (float*)(ws + OFF_MEAND);
    float* g1     = (float*)(ws + OFF_G1);
    float* d1     = (float*)(ws + OFF_D1);

    const int E = in_sizes[2];              // 1,000,000
    const int eblocks = (E + 255) / 256;

    // zero counts + cursors (contiguous regions)
    hipMemsetAsync(ws, 0, 360000, stream);

    // build combined CSR
    count_deg<<<eblocks, 256, 0, stream>>>(src, dst, cnt, E);
    scan1<<<NSCAN_BLOCKS, 256, 0, stream>>>(cnt, row, bsum, NTOT);
    scan2<<<NSCAN_BLOCKS, 256, 0, stream>>>(row, bsum, NTOT, 2 * E);
    fill_csr<<<eblocks, 256, 0, stream>>>(src, dst, row, cur, col, E);

    // ---- layer 1 ----
    agg_mean<<<(ND + 3) / 4, 256, 0, stream>>>(x_g, row, col, mean_d, ND);       // disease <- mean(genes)
    agg_mean<<<(NG + 3) / 4, 256, 0, stream>>>(x_d, row + ND, col, mean_g, NG);  // gene <- mean(diseases)
    gemm_dual<<<(ND + 31) / 32, 256, 0, stream>>>(mean_d, x_d, w1_gd_l, w1_gd_r, b1_gd, d1, ND);
    gemm_dual<<<(NG + 31) / 32, 256, 0, stream>>>(mean_g, x_g, w1_dg_l, w1_dg_r, b1_dg, g1, NG);

    // ---- layer 2 (reuse mean buffers) ----
    agg_mean<<<(ND + 3) / 4, 256, 0, stream>>>(g1, row, col, mean_d, ND);        // disease <- mean(g1)
    agg_mean<<<(NG + 3) / 4, 256, 0, stream>>>(d1, row + ND, col, mean_g, NG);   // gene <- mean(d1)
    gemm_dual<<<(ND + 31) / 32, 256, 0, stream>>>(mean_d, d1, w2_gd_l, w2_gd_r, b2_gd,
                                                  out, ND);                       // d2
    gemm_dual<<<(NG + 31) / 32, 256, 0, stream>>>(mean_g, g1, w2_dg_l, w2_dg_r, b2_dg,
                                                  out + (size_t)ND * 128, NG);    // g2
}

// Round 2
// 630.637 us; speedup vs baseline: 1.1965x; 1.1965x over previous
//
#include <hip/hip_runtime.h>
#include <hip/hip_fp16.h>

#define ND 25000
#define NG 20000
#define NE 1000000
#define NTOT (ND + NG)      // 45000
#define NSCAN_BLOCKS 44     // ceil(45000/1024)

// ---- workspace layout (bytes) ----
#define OFF_CNT   0ull            // NTOT int (180000 B) -- zeroed
#define OFF_CUR   180000ull       // NTOT int (180000 B) -- zeroed (contiguous with CNT)
#define OFF_ROW   360448ull       // NTOT+1 int
#define OFF_BSUM  540672ull       // 64 int
#define OFF_COL   541184ull       // 2*NE u16 (4,000,000 B)
#define OFF_XDH   4541440ull      // ND*128 half (6,400,000 B)
#define OFF_XGH   10941440ull     // NG*128 half (5,120,000 B)
#define OFF_MDH   16061568ull     // ND*128 half
#define OFF_MGH   22461568ull     // NG*128 half
#define OFF_D1H   27581568ull     // ND*128 half
#define OFF_G1H   33981568ull     // NG*128 half  (end ~39.1 MB)

// ---------------- f32 -> f16 convert (grid-stride over float4 groups) ----------------------------
__global__ __launch_bounds__(256) void cvt_h(const float* __restrict__ x,
                                             __half* __restrict__ y, int n4) {
    int i = blockIdx.x * 256 + threadIdx.x;
    int stride = gridDim.x * 256;
    for (; i < n4; i += stride) {
        float4 v = ((const float4*)x)[i];
        __half2 h0 = __floats2half2_rn(v.x, v.y);
        __half2 h1 = __floats2half2_rn(v.z, v.w);
        ((__half2*)y)[i * 2 + 0] = h0;
        ((__half2*)y)[i * 2 + 1] = h1;
    }
}

// ---------------- degree count (combined: [0,ND) = disease, [ND,NTOT) = gene) --------------------
__global__ __launch_bounds__(256) void count_deg(const int* __restrict__ src,
                                                 const int* __restrict__ dst,
                                                 int* __restrict__ cnt, int E) {
    int e = blockIdx.x * 256 + threadIdx.x;
    if (e < E) {
        atomicAdd(&cnt[src[e]], 1);
        atomicAdd(&cnt[ND + dst[e]], 1);
    }
}

// ---------------- scan pass 1 --------------------------------------------------------------------
__global__ __launch_bounds__(256) void scan1(const int* __restrict__ cnt,
                                             int* __restrict__ row,
                                             int* __restrict__ bsum, int N) {
    __shared__ int sd[256];
    int t = threadIdx.x;
    int base = blockIdx.x * 1024 + t * 4;
    int v[4];
#pragma unroll
    for (int j = 0; j < 4; ++j) {
        int idx = base + j;
        v[j] = (idx < N) ? cnt[idx] : 0;
    }
    int tsum = v[0] + v[1] + v[2] + v[3];
    sd[t] = tsum;
    __syncthreads();
    for (int off = 1; off < 256; off <<= 1) {
        int x = (t >= off) ? sd[t - off] : 0;
        __syncthreads();
        sd[t] += x;
        __syncthreads();
    }
    int run = sd[t] - tsum;
#pragma unroll
    for (int j = 0; j < 4; ++j) {
        int idx = base + j;
        if (idx < N) row[idx] = run;
        run += v[j];
    }
    if (t == 255) bsum[blockIdx.x] = sd[255];
}

// ---------------- scan pass 2 --------------------------------------------------------------------
__global__ __launch_bounds__(256) void scan2(int* __restrict__ row,
                                             const int* __restrict__ bsum,
                                             int N, int total) {
    int off = 0;
    for (int b2 = 0; b2 < (int)blockIdx.x; ++b2) off += bsum[b2];
    int t = threadIdx.x;
    int base = blockIdx.x * 1024 + t * 4;
#pragma unroll
    for (int j = 0; j < 4; ++j) {
        int idx = base + j;
        if (idx < N) row[idx] += off;
    }
    if (blockIdx.x == 0 && t == 0) row[N] = total;
}

// ---------------- CSR fill (u16 columns) ---------------------------------------------------------
__global__ __launch_bounds__(256) void fill_csr(const int* __restrict__ src,
                                                const int* __restrict__ dst,
                                                const int* __restrict__ row,
                                                int* __restrict__ cur,
                                                unsigned short* __restrict__ col, int E) {
    int e = blockIdx.x * 256 + threadIdx.x;
    if (e < E) {
        int s = src[e], d = dst[e];
        int p = row[s] + atomicAdd(&cur[s], 1);
        col[p] = (unsigned short)d;                  // disease row: gene neighbors
        int q = row[ND + d] + atomicAdd(&cur[ND + d], 1);
        col[q] = (unsigned short)s;                  // gene row: disease neighbors
    }
}

// ---------------- fp16 mean aggregation: one wave per node, half2 per lane -----------------------
__global__ __launch_bounds__(256) void agg_mean_h(const __half* __restrict__ X,
                                                  const int* __restrict__ rowptr,
                                                  const unsigned short* __restrict__ col,
                                                  __half* __restrict__ out, int n) {
    int wid = threadIdx.x >> 6;
    int lane = threadIdx.x & 63;
    int node = blockIdx.x * 4 + wid;
    if (node >= n) return;
    int b = rowptr[node], e = rowptr[node + 1];
    const __half2* xp = (const __half2*)X;
    float sx = 0.f, sy = 0.f;
    int j = b;
    for (; j + 4 <= e; j += 4) {
        int c0 = col[j], c1 = col[j + 1], c2 = col[j + 2], c3 = col[j + 3];
        float2 v0 = __half22float2(xp[(size_t)c0 * 64 + lane]);
        float2 v1 = __half22float2(xp[(size_t)c1 * 64 + lane]);
        float2 v2 = __half22float2(xp[(size_t)c2 * 64 + lane]);
        float2 v3 = __half22float2(xp[(size_t)c3 * 64 + lane]);
        sx += (v0.x + v1.x) + (v2.x + v3.x);
        sy += (v0.y + v1.y) + (v2.y + v3.y);
    }
    for (; j < e; ++j) {
        int c = col[j];
        float2 v = __half22float2(xp[(size_t)c * 64 + lane]);
        sx += v.x;
        sy += v.y;
    }
    int deg = e - b;
    float r = 1.0f / (float)(deg > 0 ? deg : 1);
    ((__half2*)out)[(size_t)node * 64 + lane] = __floats2half2_rn(sx * r, sy * r);
}

// ---------------- dual GEMM: Y = A1@W1 + A2@W2 + b (A fp16, W f32) -------------------------------
// block=256, 32 rows/block; A tiles converted to f32 + transposed in LDS; 4x4 micro-tile/thread.
// Writes f32 to Yf if non-null, fp16 to Yh if non-null.
__global__ __launch_bounds__(256) void gemm_dual(const __half* __restrict__ A1h,
                                                 const __half* __restrict__ A2h,
                                                 const float* __restrict__ W1,
                                                 const float* __restrict__ W2,
                                                 const float* __restrict__ bias,
                                                 float* __restrict__ Yf,
                                                 __half* __restrict__ Yh, int n) {
    __shared__ __align__(16) float aT1[128 * 32];
    __shared__ __align__(16) float aT2[128 * 32];
    int t = threadIdx.x;
    int n0 = blockIdx.x * 32;

    {
        int nl = t & 31;     // local node 0..31
        int kc = t >> 5;     // 0..7, 16 k each
        int node = n0 + nl;
        bool ok = node < n;
        const __half* a1p = A1h + (size_t)(ok ? node : 0) * 128;
        const __half* a2p = A2h + (size_t)(ok ? node : 0) * 128;
#pragma unroll
        for (int q = 0; q < 2; ++q) {
            int k = kc * 16 + q * 8;
            float4 r1 = ok ? *(const float4*)(a1p + k) : make_float4(0.f, 0.f, 0.f, 0.f);
            float4 r2 = ok ? *(const float4*)(a2p + k) : make_float4(0.f, 0.f, 0.f, 0.f);
            const __half2* h1 = (const __half2*)&r1;
            const __half2* h2 = (const __half2*)&r2;
#pragma unroll
            for (int m = 0; m < 4; ++m) {
                float2 f1 = __half22float2(h1[m]);
                float2 f2 = __half22float2(h2[m]);
                aT1[(k + 2 * m + 0) * 32 + nl] = f1.x;
                aT1[(k + 2 * m + 1) * 32 + nl] = f1.y;
                aT2[(k + 2 * m + 0) * 32 + nl] = f2.x;
                aT2[(k + 2 * m + 1) * 32 + nl] = f2.y;
            }
        }
    }
    __syncthreads();

    int fg = t & 31;        // features 4fg..4fg+3
    int ng = t >> 5;        // local nodes 4ng..4ng+3
    int ng4 = ng * 4;
    float acc[4][4];
#pragma unroll
    for (int i = 0; i < 4; ++i)
#pragma unroll
        for (int j = 0; j < 4; ++j) acc[i][j] = 0.f;

    const float4* Wp1 = (const float4*)W1 + fg;
    const float4* Wp2 = (const float4*)W2 + fg;

#pragma unroll 4
    for (int k = 0; k < 128; ++k) {
        float4 w1 = Wp1[k * 32];
        float4 w2 = Wp2[k * 32];
        float4 a1 = *(const float4*)&aT1[k * 32 + ng4];
        float4 a2 = *(const float4*)&aT2[k * 32 + ng4];
        float av1[4] = {a1.x, a1.y, a1.z, a1.w};
        float av2[4] = {a2.x, a2.y, a2.z, a2.w};
        float wv1[4] = {w1.x, w1.y, w1.z, w1.w};
        float wv2[4] = {w2.x, w2.y, w2.z, w2.w};
#pragma unroll
        for (int i = 0; i < 4; ++i)
#pragma unroll
            for (int j = 0; j < 4; ++j)
                acc[i][j] += av1[i] * wv1[j] + av2[i] * wv2[j];
    }

    float4 bb = ((const float4*)bias)[fg];
#pragma unroll
    for (int i = 0; i < 4; ++i) {
        int node = n0 + ng4 + i;
        if (node < n) {
            float o0 = acc[i][0] + bb.x;
            float o1 = acc[i][1] + bb.y;
            float o2 = acc[i][2] + bb.z;
            float o3 = acc[i][3] + bb.w;
            if (Yf) {
                float4 o = make_float4(o0, o1, o2, o3);
                *(float4*)(Yf + (size_t)node * 128 + fg * 4) = o;
            }
            if (Yh) {
                __half2* dsth = (__half2*)(Yh + (size_t)node * 128 + fg * 4);
                dsth[0] = __floats2half2_rn(o0, o1);
                dsth[1] = __floats2half2_rn(o2, o3);
            }
        }
    }
}

extern "C" void kernel_launch(void* const* d_in, const int* in_sizes, int n_in,
                              void* d_out, int out_size, void* d_ws, size_t ws_size,
                              hipStream_t stream) {
    const float* x_d     = (const float*)d_in[0];
    const float* x_g     = (const float*)d_in[1];
    const int*   src     = (const int*)d_in[2];
    const int*   dst     = (const int*)d_in[3];
    const float* w1_dg_l = (const float*)d_in[4];
    const float* b1_dg   = (const float*)d_in[5];
    const float* w1_dg_r = (const float*)d_in[6];
    const float* w1_gd_l = (const float*)d_in[7];
    const float* b1_gd   = (const float*)d_in[8];
    const float* w1_gd_r = (const float*)d_in[9];
    const float* w2_dg_l = (const float*)d_in[10];
    const float* b2_dg   = (const float*)d_in[11];
    const float* w2_dg_r = (const float*)d_in[12];
    const float* w2_gd_l = (const float*)d_in[13];
    const float* b2_gd   = (const float*)d_in[14];
    const float* w2_gd_r = (const float*)d_in[15];
    float* out = (float*)d_out;

    char* ws = (char*)d_ws;
    int*            cnt    = (int*)(ws + OFF_CNT);
    int*            cur    = (int*)(ws + OFF_CUR);
    int*            row    = (int*)(ws + OFF_ROW);
    int*            bsum   = (int*)(ws + OFF_BSUM);
    unsigned short* col    = (unsigned short*)(ws + OFF_COL);
    __half*         xd_h   = (__half*)(ws + OFF_XDH);
    __half*         xg_h   = (__half*)(ws + OFF_XGH);
    __half*         md_h   = (__half*)(ws + OFF_MDH);
    __half*         mg_h   = (__half*)(ws + OFF_MGH);
    __half*         d1_h   = (__half*)(ws + OFF_D1H);
    __half*         g1_h   = (__half*)(ws + OFF_G1H);

    const int E = in_sizes[2];              // 1,000,000
    const int eblocks = (E + 255) / 256;

    // zero counts + cursors (contiguous)
    hipMemsetAsync(ws, 0, 360000, stream);

    // convert inputs to fp16
    cvt_h<<<(ND * 32 + 255) / 256, 256, 0, stream>>>(x_d, xd_h, ND * 32);
    cvt_h<<<(NG * 32 + 255) / 256, 256, 0, stream>>>(x_g, xg_h, NG * 32);

    // build combined CSR (u16 cols)
    count_deg<<<eblocks, 256, 0, stream>>>(src, dst, cnt, E);
    scan1<<<NSCAN_BLOCKS, 256, 0, stream>>>(cnt, row, bsum, NTOT);
    scan2<<<NSCAN_BLOCKS, 256, 0, stream>>>(row, bsum, NTOT, 2 * E);
    fill_csr<<<eblocks, 256, 0, stream>>>(src, dst, row, cur, col, E);

    // ---- layer 1 ----
    agg_mean_h<<<(ND + 3) / 4, 256, 0, stream>>>(xg_h, row, col, md_h, ND);       // disease <- mean(genes)
    agg_mean_h<<<(NG + 3) / 4, 256, 0, stream>>>(xd_h, row + ND, col, mg_h, NG);  // gene <- mean(diseases)
    gemm_dual<<<(ND + 31) / 32, 256, 0, stream>>>(md_h, xd_h, w1_gd_l, w1_gd_r, b1_gd,
                                                  (float*)nullptr, d1_h, ND);
    gemm_dual<<<(NG + 31) / 32, 256, 0, stream>>>(mg_h, xg_h, w1_dg_l, w1_dg_r, b1_dg,
                                                  (float*)nullptr, g1_h, NG);

    // ---- layer 2 (reuse mean buffers) ----
    agg_mean_h<<<(ND + 3) / 4, 256, 0, stream>>>(g1_h, row, col, md_h, ND);       // disease <- mean(g1)
    agg_mean_h<<<(NG + 3) / 4, 256, 0, stream>>>(d1_h, row + ND, col, mg_h, NG);  // gene <- mean(d1)
    gemm_dual<<<(ND + 31) / 32, 256, 0, stream>>>(md_h, d1_h, w2_gd_l, w2_gd_r, b2_gd,
                                                  out, (__half*)nullptr, ND);                     // d2
    gemm_dual<<<(NG + 31) / 32, 256, 0, stream>>>(mg_h, g1_h, w2_dg_l, w2_dg_r, b2_dg,
                                                  out + (size_t)ND * 128, (__half*)nullptr, NG);  // g2
}

// Round 3
// 499.945 us; speedup vs baseline: 1.5093x; 1.2614x over previous
//
#include <hip/hip_runtime.h>
#include <hip/hip_fp16.h>

#define ND 25000
#define NG 20000
#define NTOT (ND + NG)      // 45000
#define NSCAN_BLOCKS 44     // ceil(45000/1024)

typedef _Float16 half8 __attribute__((ext_vector_type(8)));
typedef float f32x4 __attribute__((ext_vector_type(4)));

// ---- workspace layout (bytes), 256B-aligned ----
#define OFF_CNT   0ull            // NTOT int (180000) -- zeroed
#define OFF_CUR   180000ull       // NTOT int (180000) -- zeroed (contiguous with CNT)
#define OFF_ROW   360448ull       // NTOT+1 int
#define OFF_BSUM  540672ull       // 64 int
#define OFF_COL   541184ull       // 2*NE u16 (4,000,000)
#define OFF_WSW   4541440ull      // 8 * 128*128 half (262144)
#define OFF_XDH   4803584ull      // ND*128 half (6,400,000)
#define OFF_XGH   11203584ull     // NG*128 half (5,120,000)
#define OFF_MDH   16323584ull     // ND*128 half
#define OFF_MGH   22723584ull     // NG*128 half
#define OFF_D1H   27843584ull     // ND*128 half
#define OFF_G1H   34243584ull     // NG*128 half  (end ~39.4 MB)

// ---------------- f32 -> f16 convert -------------------------------------------------------------
__global__ __launch_bounds__(256) void cvt_h(const float* __restrict__ x,
                                             __half* __restrict__ y, int n4) {
    int i = blockIdx.x * 256 + threadIdx.x;
    int stride = gridDim.x * 256;
    for (; i < n4; i += stride) {
        float4 v = ((const float4*)x)[i];
        ((__half2*)y)[i * 2 + 0] = __floats2half2_rn(v.x, v.y);
        ((__half2*)y)[i * 2 + 1] = __floats2half2_rn(v.z, v.w);
    }
}

// ---------------- W swizzle: f32 [128][128] row-major -> fp16 MFMA B-fragment layout -------------
// slot = (ntile*4+kc)*64 + lane; element j of slot = W[kc*32+(lane>>4)*8+j][ntile*16+(lane&15)]
struct WPtrs { const float* w[8]; };
__global__ __launch_bounds__(256) void swz_w(WPtrs p, _Float16* __restrict__ dst) {
    int mat = blockIdx.x;            // 0..7
    const float* W = p.w[mat];
    _Float16* o = dst + (size_t)mat * 16384;
    int t = threadIdx.x;
    for (int rep = 0; rep < 8; ++rep) {
        int slot = rep * 256 + t;    // 0..2047
        int lane = slot & 63, grp = slot >> 6;   // grp = ntile*4+kc
        int kc = grp & 3, ntile = grp >> 2;
        int nn = ntile * 16 + (lane & 15);
        int kb = kc * 32 + (lane >> 4) * 8;
        half8 v;
#pragma unroll
        for (int j = 0; j < 8; ++j) v[j] = (_Float16)W[(size_t)(kb + j) * 128 + nn];
        *(half8*)(o + (size_t)slot * 8) = v;
    }
}

// ---------------- degree count (2 edges / thread) ------------------------------------------------
__global__ __launch_bounds__(256) void count_deg(const int* __restrict__ src,
                                                 const int* __restrict__ dst,
                                                 int* __restrict__ cnt, int E) {
    int e2 = blockIdx.x * 256 + threadIdx.x;
    int E2 = E >> 1;
    if (e2 < E2) {
        int2 s = ((const int2*)src)[e2];
        int2 d = ((const int2*)dst)[e2];
        atomicAdd(&cnt[s.x], 1);
        atomicAdd(&cnt[s.y], 1);
        atomicAdd(&cnt[ND + d.x], 1);
        atomicAdd(&cnt[ND + d.y], 1);
    } else if (e2 == E2 && (E & 1)) {
        atomicAdd(&cnt[src[E - 1]], 1);
        atomicAdd(&cnt[ND + dst[E - 1]], 1);
    }
}

// ---------------- scan pass 1 --------------------------------------------------------------------
__global__ __launch_bounds__(256) void scan1(const int* __restrict__ cnt,
                                             int* __restrict__ row,
                                             int* __restrict__ bsum, int N) {
    __shared__ int sd[256];
    int t = threadIdx.x;
    int base = blockIdx.x * 1024 + t * 4;
    int v[4];
#pragma unroll
    for (int j = 0; j < 4; ++j) {
        int idx = base + j;
        v[j] = (idx < N) ? cnt[idx] : 0;
    }
    int tsum = v[0] + v[1] + v[2] + v[3];
    sd[t] = tsum;
    __syncthreads();
    for (int off = 1; off < 256; off <<= 1) {
        int x = (t >= off) ? sd[t - off] : 0;
        __syncthreads();
        sd[t] += x;
        __syncthreads();
    }
    int run = sd[t] - tsum;
#pragma unroll
    for (int j = 0; j < 4; ++j) {
        int idx = base + j;
        if (idx < N) row[idx] = run;
        run += v[j];
    }
    if (t == 255) bsum[blockIdx.x] = sd[255];
}

// ---------------- scan pass 2 --------------------------------------------------------------------
__global__ __launch_bounds__(256) void scan2(int* __restrict__ row,
                                             const int* __restrict__ bsum,
                                             int N, int total) {
    int off = 0;
    for (int b2 = 0; b2 < (int)blockIdx.x; ++b2) off += bsum[b2];
    int t = threadIdx.x;
    int base = blockIdx.x * 1024 + t * 4;
#pragma unroll
    for (int j = 0; j < 4; ++j) {
        int idx = base + j;
        if (idx < N) row[idx] += off;
    }
    if (blockIdx.x == 0 && t == 0) row[N] = total;
}

// ---------------- CSR fill, disease rows only (2 MB scatter target) ------------------------------
__global__ __launch_bounds__(256) void fill_d(const int* __restrict__ src,
                                              const int* __restrict__ dst,
                                              const int* __restrict__ row,
                                              int* __restrict__ cur,
                                              unsigned short* __restrict__ col, int E) {
    int e2 = blockIdx.x * 256 + threadIdx.x;
    int E2 = E >> 1;
    if (e2 < E2) {
        int2 s = ((const int2*)src)[e2];
        int2 d = ((const int2*)dst)[e2];
        int p0 = row[s.x] + atomicAdd(&cur[s.x], 1);
        col[p0] = (unsigned short)d.x;
        int p1 = row[s.y] + atomicAdd(&cur[s.y], 1);
        col[p1] = (unsigned short)d.y;
    } else if (e2 == E2 && (E & 1)) {
        int s = src[E - 1], d = dst[E - 1];
        int p = row[s] + atomicAdd(&cur[s], 1);
        col[p] = (unsigned short)d;
    }
}

// ---------------- CSR fill, gene rows only -------------------------------------------------------
__global__ __launch_bounds__(256) void fill_g(const int* __restrict__ src,
                                              const int* __restrict__ dst,
                                              const int* __restrict__ row,
                                              int* __restrict__ cur,
                                              unsigned short* __restrict__ col, int E) {
    int e2 = blockIdx.x * 256 + threadIdx.x;
    int E2 = E >> 1;
    if (e2 < E2) {
        int2 s = ((const int2*)src)[e2];
        int2 d = ((const int2*)dst)[e2];
        int q0 = row[ND + d.x] + atomicAdd(&cur[ND + d.x], 1);
        col[q0] = (unsigned short)s.x;
        int q1 = row[ND + d.y] + atomicAdd(&cur[ND + d.y], 1);
        col[q1] = (unsigned short)s.y;
    } else if (e2 == E2 && (E & 1)) {
        int s = src[E - 1], d = dst[E - 1];
        int q = row[ND + d] + atomicAdd(&cur[ND + d], 1);
        col[q] = (unsigned short)s;
    }
}

// ---------------- fp16 mean aggregation: one wave per node, half2 per lane -----------------------
__global__ __launch_bounds__(256) void agg_mean_h(const __half* __restrict__ X,
                                                  const int* __restrict__ rowptr,
                                                  const unsigned short* __restrict__ col,
                                                  __half* __restrict__ out, int n) {
    int wid = threadIdx.x >> 6;
    int lane = threadIdx.x & 63;
    int node = blockIdx.x * 4 + wid;
    if (node >= n) return;
    int b = rowptr[node], e = rowptr[node + 1];
    const __half2* xp = (const __half2*)X;
    float sx = 0.f, sy = 0.f;
    int j = b;
    for (; j + 4 <= e; j += 4) {
        int c0 = col[j], c1 = col[j + 1], c2 = col[j + 2], c3 = col[j + 3];
        float2 v0 = __half22float2(xp[(size_t)c0 * 64 + lane]);
        float2 v1 = __half22float2(xp[(size_t)c1 * 64 + lane]);
        float2 v2 = __half22float2(xp[(size_t)c2 * 64 + lane]);
        float2 v3 = __half22float2(xp[(size_t)c3 * 64 + lane]);
        sx += (v0.x + v1.x) + (v2.x + v3.x);
        sy += (v0.y + v1.y) + (v2.y + v3.y);
    }
    for (; j < e; ++j) {
        int c = col[j];
        float2 v = __half22float2(xp[(size_t)c * 64 + lane]);
        sx += v.x;
        sy += v.y;
    }
    int deg = e - b;
    float r = 1.0f / (float)(deg > 0 ? deg : 1);
    ((__half2*)out)[(size_t)node * 64 + lane] = __floats2half2_rn(sx * r, sy * r);
}

// ---------------- MFMA dual GEMM: Y = A1@W1 + A2@W2 + b ------------------------------------------
// 256 thr = 4 waves, 64 rows/block (16/wave). No LDS: A frags loaded per lane,
// W pre-swizzled to B-frag layout (L1-resident, coalesced half8 loads).
// A-frag: A[m=lane&15][k=kc*32+(lane>>4)*8+j]; C/D: col=lane&15, row=(lane>>4)*4+reg.
__global__ __launch_bounds__(256) void gemm_mfma(const __half* __restrict__ A1,
                                                 const __half* __restrict__ A2,
                                                 const _Float16* __restrict__ Wsw1,
                                                 const _Float16* __restrict__ Wsw2,
                                                 const float* __restrict__ bias,
                                                 float* __restrict__ Yf,
                                                 __half* __restrict__ Yh, int n) {
    int t = threadIdx.x;
    int wave = t >> 6, lane = t & 63;
    int row0 = blockIdx.x * 64 + wave * 16;
    if (row0 >= n) return;
    int m = lane & 15, quad = lane >> 4;
    int arow = row0 + m;
    if (arow >= n) arow = n - 1;
    const _Float16* a1p = (const _Float16*)A1 + (size_t)arow * 128 + quad * 8;
    const _Float16* a2p = (const _Float16*)A2 + (size_t)arow * 128 + quad * 8;
    half8 a1[4], a2[4];
#pragma unroll
    for (int kc = 0; kc < 4; ++kc) {
        a1[kc] = *(const half8*)(a1p + kc * 32);
        a2[kc] = *(const half8*)(a2p + kc * 32);
    }
#pragma unroll
    for (int ntile = 0; ntile < 8; ++ntile) {
        f32x4 acc = {0.f, 0.f, 0.f, 0.f};
#pragma unroll
        for (int kc = 0; kc < 4; ++kc) {
            half8 b1 = *(const half8*)(Wsw1 + (size_t)((ntile * 4 + kc) * 64 + lane) * 8);
            acc = __builtin_amdgcn_mfma_f32_16x16x32_f16(a1[kc], b1, acc, 0, 0, 0);
            half8 b2 = *(const half8*)(Wsw2 + (size_t)((ntile * 4 + kc) * 64 + lane) * 8);
            acc = __builtin_amdgcn_mfma_f32_16x16x32_f16(a2[kc], b2, acc, 0, 0, 0);
        }
        int colx = ntile * 16 + m;
        float bb = bias[colx];
#pragma unroll
        for (int r = 0; r < 4; ++r) {
            int rr = row0 + quad * 4 + r;
            if (rr < n) {
                float v = acc[r] + bb;
                if (Yf) Yf[(size_t)rr * 128 + colx] = v;
                else    Yh[(size_t)rr * 128 + colx] = __float2half(v);
            }
        }
    }
}

extern "C" void kernel_launch(void* const* d_in, const int* in_sizes, int n_in,
                              void* d_out, int out_size, void* d_ws, size_t ws_size,
                              hipStream_t stream) {
    const float* x_d     = (const float*)d_in[0];
    const float* x_g     = (const float*)d_in[1];
    const int*   src     = (const int*)d_in[2];
    const int*   dst     = (const int*)d_in[3];
    const float* w1_dg_l = (const float*)d_in[4];
    const float* b1_dg   = (const float*)d_in[5];
    const float* w1_dg_r = (const float*)d_in[6];
    const float* w1_gd_l = (const float*)d_in[7];
    const float* b1_gd   = (const float*)d_in[8];
    const float* w1_gd_r = (const float*)d_in[9];
    const float* w2_dg_l = (const float*)d_in[10];
    const float* b2_dg   = (const float*)d_in[11];
    const float* w2_dg_r = (const float*)d_in[12];
    const float* w2_gd_l = (const float*)d_in[13];
    const float* b2_gd   = (const float*)d_in[14];
    const float* w2_gd_r = (const float*)d_in[15];
    float* out = (float*)d_out;

    char* ws = (char*)d_ws;
    int*            cnt  = (int*)(ws + OFF_CNT);
    int*            cur  = (int*)(ws + OFF_CUR);
    int*            row  = (int*)(ws + OFF_ROW);
    int*            bsum = (int*)(ws + OFF_BSUM);
    unsigned short* col  = (unsigned short*)(ws + OFF_COL);
    _Float16*       wsw  = (_Float16*)(ws + OFF_WSW);
    __half*         xd_h = (__half*)(ws + OFF_XDH);
    __half*         xg_h = (__half*)(ws + OFF_XGH);
    __half*         md_h = (__half*)(ws + OFF_MDH);
    __half*         mg_h = (__half*)(ws + OFF_MGH);
    __half*         d1_h = (__half*)(ws + OFF_D1H);
    __half*         g1_h = (__half*)(ws + OFF_G1H);

    const int E = in_sizes[2];              // 1,000,000
    const int e2blocks = ((E >> 1) + 256) / 256;   // covers tail thread too

    hipMemsetAsync(ws, 0, 360000, stream);  // cnt + cur

    // fp16 conversions + weight swizzle
    cvt_h<<<(ND * 32 + 255) / 256, 256, 0, stream>>>(x_d, xd_h, ND * 32);
    cvt_h<<<(NG * 32 + 255) / 256, 256, 0, stream>>>(x_g, xg_h, NG * 32);
    WPtrs wp;
    wp.w[0] = w1_dg_l; wp.w[1] = w1_dg_r; wp.w[2] = w1_gd_l; wp.w[3] = w1_gd_r;
    wp.w[4] = w2_dg_l; wp.w[5] = w2_dg_r; wp.w[6] = w2_gd_l; wp.w[7] = w2_gd_r;
    swz_w<<<8, 256, 0, stream>>>(wp, wsw);

    // combined CSR build (u16 cols), scatters split per node type
    count_deg<<<e2blocks, 256, 0, stream>>>(src, dst, cnt, E);
    scan1<<<NSCAN_BLOCKS, 256, 0, stream>>>(cnt, row, bsum, NTOT);
    scan2<<<NSCAN_BLOCKS, 256, 0, stream>>>(row, bsum, NTOT, 2 * E);
    fill_d<<<e2blocks, 256, 0, stream>>>(src, dst, row, cur, col, E);
    fill_g<<<e2blocks, 256, 0, stream>>>(src, dst, row, cur, col, E);

    // ---- layer 1 ----
    agg_mean_h<<<(ND + 3) / 4, 256, 0, stream>>>(xg_h, row, col, md_h, ND);       // disease <- mean(genes)
    agg_mean_h<<<(NG + 3) / 4, 256, 0, stream>>>(xd_h, row + ND, col, mg_h, NG);  // gene <- mean(diseases)
    gemm_mfma<<<(ND + 63) / 64, 256, 0, stream>>>(md_h, xd_h, wsw + 2 * 16384, wsw + 3 * 16384,
                                                  b1_gd, (float*)nullptr, d1_h, ND);
    gemm_mfma<<<(NG + 63) / 64, 256, 0, stream>>>(mg_h, xg_h, wsw + 0 * 16384, wsw + 1 * 16384,
                                                  b1_dg, (float*)nullptr, g1_h, NG);

    // ---- layer 2 ----
    agg_mean_h<<<(ND + 3) / 4, 256, 0, stream>>>(g1_h, row, col, md_h, ND);       // disease <- mean(g1)
    agg_mean_h<<<(NG + 3) / 4, 256, 0, stream>>>(d1_h, row + ND, col, mg_h, NG);  // gene <- mean(d1)
    gemm_mfma<<<(ND + 63) / 64, 256, 0, stream>>>(md_h, d1_h, wsw + 6 * 16384, wsw + 7 * 16384,
                                                  b2_gd, out, (__half*)nullptr, ND);                     // d2
    gemm_mfma<<<(NG + 63) / 64, 256, 0, stream>>>(mg_h, g1_h, wsw + 4 * 16384, wsw + 5 * 16384,
                                                  b2_dg, out + (size_t)ND * 128, (__half*)nullptr, NG);  // g2
}

// Round 4
// 424.216 us; speedup vs baseline: 1.7787x; 1.1785x over previous
//
#include <hip/hip_runtime.h>
#include <hip/hip_fp16.h>

#define ND 25000
#define NG 20000
#define NTOT (ND + NG)      // 45000
#define NSCAN_BLOCKS 44     // ceil(45000/1024)
#define NBLK 64             // histogram / fill privatization blocks

typedef _Float16 half8 __attribute__((ext_vector_type(8)));
typedef float f32x4 __attribute__((ext_vector_type(4)));

// ---- workspace layout (bytes), 256B-aligned ----
#define OFF_CNT    0ull           // NTOT int (180000)
#define OFF_ROW    180224ull      // NTOT+1 int
#define OFF_BSUM   360448ull      // 64 int
#define OFF_PARTD  360704ull      // NBLK*ND u16 (3,200,000)
#define OFF_PARTG  3560704ull     // NBLK*NG u16 (2,560,000)
#define OFF_COL    6120704ull     // 2*NE u16 (4,000,000)
#define OFF_WSW    10120704ull    // 8*128*128 half (262144)
#define OFF_XDH    10382848ull    // ND*128 half (6,400,000)
#define OFF_XGH    16782848ull    // NG*128 half (5,120,000)
#define OFF_MDH    21902848ull    // ND*128 half
#define OFF_MGH    28302848ull    // NG*128 half
#define OFF_D1H    33422848ull    // ND*128 half
#define OFF_G1H    39822848ull    // NG*128 half   (end ~44.9 MB)

// ---------------- f32 -> f16 convert -------------------------------------------------------------
__global__ __launch_bounds__(256) void cvt_h(const float* __restrict__ x,
                                             __half* __restrict__ y, int n4) {
    int i = blockIdx.x * 256 + threadIdx.x;
    int stride = gridDim.x * 256;
    for (; i < n4; i += stride) {
        float4 v = ((const float4*)x)[i];
        ((__half2*)y)[i * 2 + 0] = __floats2half2_rn(v.x, v.y);
        ((__half2*)y)[i * 2 + 1] = __floats2half2_rn(v.z, v.w);
    }
}

// ---------------- W swizzle: f32 [128][128] row-major -> fp16 MFMA B-fragment layout -------------
struct WPtrs { const float* w[8]; };
__global__ __launch_bounds__(256) void swz_w(WPtrs p, _Float16* __restrict__ dst) {
    int mat = blockIdx.x;            // 0..7
    const float* W = p.w[mat];
    _Float16* o = dst + (size_t)mat * 16384;
    int t = threadIdx.x;
    for (int rep = 0; rep < 8; ++rep) {
        int slot = rep * 256 + t;    // 0..2047
        int lane = slot & 63, grp = slot >> 6;   // grp = ntile*4+kc
        int kc = grp & 3, ntile = grp >> 2;
        int nn = ntile * 16 + (lane & 15);
        int kb = kc * 32 + (lane >> 4) * 8;
        half8 v;
#pragma unroll
        for (int j = 0; j < 8; ++j) v[j] = (_Float16)W[(size_t)(kb + j) * 128 + nn];
        *(half8*)(o + (size_t)slot * 8) = v;
    }
}

// ---------------- privatized histogram: NBLK blocks, packed u16 bins in LDS ----------------------
// part[b][k] (u16 row-major, coalesced flush). Per-block count <= slice < 65536.
template <int NBINS>
__global__ __launch_bounds__(256) void hist_priv(const int* __restrict__ key,
                                                 unsigned short* __restrict__ part, int E) {
    constexpr int NW = NBINS / 2;
    __shared__ unsigned int h[NW];
    int t = threadIdx.x, b = blockIdx.x;
    for (int i = t; i < NW; i += 256) h[i] = 0;
    __syncthreads();
    int e0 = (int)(((long long)E * b) / NBLK);
    int e1 = (int)(((long long)E * (b + 1)) / NBLK);
    for (int e = e0 + t; e < e1; e += 256) {
        int k = key[e];
        atomicAdd(&h[k >> 1], 1u << ((k & 1) * 16));
    }
    __syncthreads();
    unsigned int* po = (unsigned int*)(part + (size_t)b * NBINS);
    for (int i = t; i < NW; i += 256) po[i] = h[i];
}

// ---------------- column scan over partials: part[b][k] -> exclusive base; cnt[k] = total --------
__global__ __launch_bounds__(256) void colscan(unsigned short* __restrict__ part,
                                               int* __restrict__ cnt, int nbins) {
    int k = blockIdx.x * 256 + threadIdx.x;
    if (k >= nbins) return;
    int run = 0;
#pragma unroll 8
    for (int b = 0; b < NBLK; ++b) {
        size_t idx = (size_t)b * nbins + k;
        int v = part[idx];
        part[idx] = (unsigned short)run;
        run += v;
    }
    cnt[k] = run;
}

// ---------------- scan pass 1 (1024 elems/block) -------------------------------------------------
__global__ __launch_bounds__(256) void scan1(const int* __restrict__ cnt,
                                             int* __restrict__ row,
                                             int* __restrict__ bsum, int N) {
    __shared__ int sd[256];
    int t = threadIdx.x;
    int base = blockIdx.x * 1024 + t * 4;
    int v[4];
#pragma unroll
    for (int j = 0; j < 4; ++j) {
        int idx = base + j;
        v[j] = (idx < N) ? cnt[idx] : 0;
    }
    int tsum = v[0] + v[1] + v[2] + v[3];
    sd[t] = tsum;
    __syncthreads();
    for (int off = 1; off < 256; off <<= 1) {
        int x = (t >= off) ? sd[t - off] : 0;
        __syncthreads();
        sd[t] += x;
        __syncthreads();
    }
    int run = sd[t] - tsum;
#pragma unroll
    for (int j = 0; j < 4; ++j) {
        int idx = base + j;
        if (idx < N) row[idx] = run;
        run += v[j];
    }
    if (t == 255) bsum[blockIdx.x] = sd[255];
}

// ---------------- scan pass 2 --------------------------------------------------------------------
__global__ __launch_bounds__(256) void scan2(int* __restrict__ row,
                                             const int* __restrict__ bsum,
                                             int N, int total) {
    int off = 0;
    for (int b2 = 0; b2 < (int)blockIdx.x; ++b2) off += bsum[b2];
    int t = threadIdx.x;
    int base = blockIdx.x * 1024 + t * 4;
#pragma unroll
    for (int j = 0; j < 4; ++j) {
        int idx = base + j;
        if (idx < N) row[idx] += off;
    }
    if (blockIdx.x == 0 && t == 0) row[N] = total;
}

// ---------------- atomic-free CSR fill: LDS base row + lds fetch_add placement -------------------
// rowp = row (+ND for gene rows). col[row[k] + base + localrank] = val.
template <int NBINS>
__global__ __launch_bounds__(256) void fill_priv(const int* __restrict__ key,
                                                 const int* __restrict__ val,
                                                 const int* __restrict__ rowp,
                                                 const unsigned short* __restrict__ part,
                                                 unsigned short* __restrict__ col, int E) {
    constexpr int NW = NBINS / 2;
    __shared__ unsigned int h[NW];
    int t = threadIdx.x, b = blockIdx.x;
    const unsigned int* pi = (const unsigned int*)(part + (size_t)b * NBINS);
    for (int i = t; i < NW; i += 256) h[i] = pi[i];
    __syncthreads();
    int e0 = (int)(((long long)E * b) / NBLK);
    int e1 = (int)(((long long)E * (b + 1)) / NBLK);
    for (int e = e0 + t; e < e1; e += 256) {
        int k = key[e];
        int v = val[e];
        unsigned int old = atomicAdd(&h[k >> 1], 1u << ((k & 1) * 16));
        int rank = (old >> ((k & 1) * 16)) & 0xffff;
        col[rowp[k] + rank] = (unsigned short)v;
    }
}

// ---------------- fp16 mean aggregation: one wave per node, half2 per lane -----------------------
__global__ __launch_bounds__(256) void agg_mean_h(const __half* __restrict__ X,
                                                  const int* __restrict__ rowptr,
                                                  const unsigned short* __restrict__ col,
                                                  __half* __restrict__ out, int n) {
    int wid = threadIdx.x >> 6;
    int lane = threadIdx.x & 63;
    int node = blockIdx.x * 4 + wid;
    if (node >= n) return;
    int b = rowptr[node], e = rowptr[node + 1];
    const __half2* xp = (const __half2*)X;
    float sx = 0.f, sy = 0.f;
    int j = b;
    for (; j + 4 <= e; j += 4) {
        int c0 = col[j], c1 = col[j + 1], c2 = col[j + 2], c3 = col[j + 3];
        float2 v0 = __half22float2(xp[(size_t)c0 * 64 + lane]);
        float2 v1 = __half22float2(xp[(size_t)c1 * 64 + lane]);
        float2 v2 = __half22float2(xp[(size_t)c2 * 64 + lane]);
        float2 v3 = __half22float2(xp[(size_t)c3 * 64 + lane]);
        sx += (v0.x + v1.x) + (v2.x + v3.x);
        sy += (v0.y + v1.y) + (v2.y + v3.y);
    }
    for (; j < e; ++j) {
        int c = col[j];
        float2 v = __half22float2(xp[(size_t)c * 64 + lane]);
        sx += v.x;
        sy += v.y;
    }
    int deg = e - b;
    float r = 1.0f / (float)(deg > 0 ? deg : 1);
    ((__half2*)out)[(size_t)node * 64 + lane] = __floats2half2_rn(sx * r, sy * r);
}

// ---------------- MFMA dual GEMM: Y = A1@W1 + A2@W2 + b ------------------------------------------
__global__ __launch_bounds__(256) void gemm_mfma(const __half* __restrict__ A1,
                                                 const __half* __restrict__ A2,
                                                 const _Float16* __restrict__ Wsw1,
                                                 const _Float16* __restrict__ Wsw2,
                                                 const float* __restrict__ bias,
                                                 float* __restrict__ Yf,
                                                 __half* __restrict__ Yh, int n) {
    int t = threadIdx.x;
    int wave = t >> 6, lane = t & 63;
    int row0 = blockIdx.x * 64 + wave * 16;
    if (row0 >= n) return;
    int m = lane & 15, quad = lane >> 4;
    int arow = row0 + m;
    if (arow >= n) arow = n - 1;
    const _Float16* a1p = (const _Float16*)A1 + (size_t)arow * 128 + quad * 8;
    const _Float16* a2p = (const _Float16*)A2 + (size_t)arow * 128 + quad * 8;
    half8 a1[4], a2[4];
#pragma unroll
    for (int kc = 0; kc < 4; ++kc) {
        a1[kc] = *(const half8*)(a1p + kc * 32);
        a2[kc] = *(const half8*)(a2p + kc * 32);
    }
#pragma unroll
    for (int ntile = 0; ntile < 8; ++ntile) {
        f32x4 acc = {0.f, 0.f, 0.f, 0.f};
#pragma unroll
        for (int kc = 0; kc < 4; ++kc) {
            half8 b1 = *(const half8*)(Wsw1 + (size_t)((ntile * 4 + kc) * 64 + lane) * 8);
            acc = __builtin_amdgcn_mfma_f32_16x16x32_f16(a1[kc], b1, acc, 0, 0, 0);
            half8 b2 = *(const half8*)(Wsw2 + (size_t)((ntile * 4 + kc) * 64 + lane) * 8);
            acc = __builtin_amdgcn_mfma_f32_16x16x32_f16(a2[kc], b2, acc, 0, 0, 0);
        }
        int colx = ntile * 16 + m;
        float bb = bias[colx];
#pragma unroll
        for (int r = 0; r < 4; ++r) {
            int rr = row0 + quad * 4 + r;
            if (rr < n) {
                float v = acc[r] + bb;
                if (Yf) Yf[(size_t)rr * 128 + colx] = v;
                else    Yh[(size_t)rr * 128 + colx] = __float2half(v);
            }
        }
    }
}

extern "C" void kernel_launch(void* const* d_in, const int* in_sizes, int n_in,
                              void* d_out, int out_size, void* d_ws, size_t ws_size,
                              hipStream_t stream) {
    const float* x_d     = (const float*)d_in[0];
    const float* x_g     = (const float*)d_in[1];
    const int*   src     = (const int*)d_in[2];
    const int*   dst     = (const int*)d_in[3];
    const float* w1_dg_l = (const float*)d_in[4];
    const float* b1_dg   = (const float*)d_in[5];
    const float* w1_dg_r = (const float*)d_in[6];
    const float* w1_gd_l = (const float*)d_in[7];
    const float* b1_gd   = (const float*)d_in[8];
    const float* w1_gd_r = (const float*)d_in[9];
    const float* w2_dg_l = (const float*)d_in[10];
    const float* b2_dg   = (const float*)d_in[11];
    const float* w2_dg_r = (const float*)d_in[12];
    const float* w2_gd_l = (const float*)d_in[13];
    const float* b2_gd   = (const float*)d_in[14];
    const float* w2_gd_r = (const float*)d_in[15];
    float* out = (float*)d_out;

    char* ws = (char*)d_ws;
    int*            cnt   = (int*)(ws + OFF_CNT);
    int*            row   = (int*)(ws + OFF_ROW);
    int*            bsum  = (int*)(ws + OFF_BSUM);
    unsigned short* partD = (unsigned short*)(ws + OFF_PARTD);
    unsigned short* partG = (unsigned short*)(ws + OFF_PARTG);
    unsigned short* col   = (unsigned short*)(ws + OFF_COL);
    _Float16*       wsw   = (_Float16*)(ws + OFF_WSW);
    __half*         xd_h  = (__half*)(ws + OFF_XDH);
    __half*         xg_h  = (__half*)(ws + OFF_XGH);
    __half*         md_h  = (__half*)(ws + OFF_MDH);
    __half*         mg_h  = (__half*)(ws + OFF_MGH);
    __half*         d1_h  = (__half*)(ws + OFF_D1H);
    __half*         g1_h  = (__half*)(ws + OFF_G1H);

    const int E = in_sizes[2];              // 1,000,000

    // fp16 conversions + weight swizzle
    cvt_h<<<(ND * 32 + 255) / 256, 256, 0, stream>>>(x_d, xd_h, ND * 32);
    cvt_h<<<(NG * 32 + 255) / 256, 256, 0, stream>>>(x_g, xg_h, NG * 32);
    WPtrs wp;
    wp.w[0] = w1_dg_l; wp.w[1] = w1_dg_r; wp.w[2] = w1_gd_l; wp.w[3] = w1_gd_r;
    wp.w[4] = w2_dg_l; wp.w[5] = w2_dg_r; wp.w[6] = w2_gd_l; wp.w[7] = w2_gd_r;
    swz_w<<<8, 256, 0, stream>>>(wp, wsw);

    // ---- CSR build: zero global atomics ----
    hist_priv<ND><<<NBLK, 256, 0, stream>>>(src, partD, E);
    hist_priv<NG><<<NBLK, 256, 0, stream>>>(dst, partG, E);
    colscan<<<(ND + 255) / 256, 256, 0, stream>>>(partD, cnt, ND);
    colscan<<<(NG + 255) / 256, 256, 0, stream>>>(partG, cnt + ND, NG);
    scan1<<<NSCAN_BLOCKS, 256, 0, stream>>>(cnt, row, bsum, NTOT);
    scan2<<<NSCAN_BLOCKS, 256, 0, stream>>>(row, bsum, NTOT, 2 * E);
    fill_priv<ND><<<NBLK, 256, 0, stream>>>(src, dst, row, partD, col, E);
    fill_priv<NG><<<NBLK, 256, 0, stream>>>(dst, src, row + ND, partG, col, E);

    // ---- layer 1 ----
    agg_mean_h<<<(ND + 3) / 4, 256, 0, stream>>>(xg_h, row, col, md_h, ND);       // disease <- mean(genes)
    agg_mean_h<<<(NG + 3) / 4, 256, 0, stream>>>(xd_h, row + ND, col, mg_h, NG);  // gene <- mean(diseases)
    gemm_mfma<<<(ND + 63) / 64, 256, 0, stream>>>(md_h, xd_h, wsw + 2 * 16384, wsw + 3 * 16384,
                                                  b1_gd, (float*)nullptr, d1_h, ND);
    gemm_mfma<<<(NG + 63) / 64, 256, 0, stream>>>(mg_h, xg_h, wsw + 0 * 16384, wsw + 1 * 16384,
                                                  b1_dg, (float*)nullptr, g1_h, NG);

    // ---- layer 2 ----
    agg_mean_h<<<(ND + 3) / 4, 256, 0, stream>>>(g1_h, row, col, md_h, ND);       // disease <- mean(g1)
    agg_mean_h<<<(NG + 3) / 4, 256, 0, stream>>>(d1_h, row + ND, col, mg_h, NG);  // gene <- mean(d1)
    gemm_mfma<<<(ND + 63) / 64, 256, 0, stream>>>(md_h, d1_h, wsw + 6 * 16384, wsw + 7 * 16384,
                                                  b2_gd, out, (__half*)nullptr, ND);                     // d2
    gemm_mfma<<<(NG + 63) / 64, 256, 0, stream>>>(mg_h, g1_h, wsw + 4 * 16384, wsw + 5 * 16384,
                                                  b2_dg, out + (size_t)ND * 128, (__half*)nullptr, NG);  // g2
}

// Round 5
// 375.129 us; speedup vs baseline: 2.0115x; 1.1309x over previous
//
#include <hip/hip_runtime.h>
#include <hip/hip_fp16.h>

#define ND 25000
#define NG 20000
#define NTOT (ND + NG)      // 45000
#define NSCAN_BLOCKS 44     // ceil(45000/1024)
#define NBLK 256            // histogram / fill privatization blocks (1 per CU)

typedef _Float16 half8 __attribute__((ext_vector_type(8)));
typedef float f32x4 __attribute__((ext_vector_type(4)));

// ---- workspace layout (bytes), 256B-aligned ----
#define OFF_CNT    0ull           // NTOT int (180000)
#define OFF_ROW    180224ull      // NTOT+1 int
#define OFF_BSUM   360448ull      // 64 int
#define OFF_PARTD  360704ull      // NBLK*ND u16 (12,800,000)
#define OFF_PARTG  13160704ull    // NBLK*NG u16 (10,240,000)
#define OFF_COL    23400704ull    // 2*NE u16 (4,000,000)
#define OFF_WSW    27400960ull    // 8*128*128 half (262,144)
#define OFF_XDH    27663360ull    // ND*128 half (6,400,000)
#define OFF_XGH    34063360ull    // NG*128 half (5,120,000)
#define OFF_MDH    39183360ull    // ND*128 half
#define OFF_MGH    45583360ull    // NG*128 half
#define OFF_D1H    50703360ull    // ND*128 half
#define OFF_G1H    57103360ull    // NG*128 half   (end ~62.2 MB)

// ---------------- f32 -> f16 convert, both inputs in one dispatch --------------------------------
__global__ __launch_bounds__(256) void cvt2(const float* __restrict__ xd,
                                            const float* __restrict__ xg,
                                            __half* __restrict__ yd,
                                            __half* __restrict__ yg) {
    const int ndq = ND * 32;            // float4 groups in x_disease
    const int tot = ndq + NG * 32;
    int i = blockIdx.x * 256 + threadIdx.x;
    if (i >= tot) return;
    const float* x;
    __half* y;
    int idx;
    if (i < ndq) { x = xd; y = yd; idx = i; }
    else         { x = xg; y = yg; idx = i - ndq; }
    float4 v = ((const float4*)x)[idx];
    ((__half2*)y)[idx * 2 + 0] = __floats2half2_rn(v.x, v.y);
    ((__half2*)y)[idx * 2 + 1] = __floats2half2_rn(v.z, v.w);
}

// ---------------- W swizzle: f32 [128][128] row-major -> fp16 MFMA B-fragment layout -------------
struct WPtrs { const float* w[8]; };
__global__ __launch_bounds__(256) void swz_w(WPtrs p, _Float16* __restrict__ dst) {
    int mat = blockIdx.x;            // 0..7
    const float* W = p.w[mat];
    _Float16* o = dst + (size_t)mat * 16384;
    int t = threadIdx.x;
    for (int rep = 0; rep < 8; ++rep) {
        int slot = rep * 256 + t;    // 0..2047
        int lane = slot & 63, grp = slot >> 6;   // grp = ntile*4+kc
        int kc = grp & 3, ntile = grp >> 2;
        int nn = ntile * 16 + (lane & 15);
        int kb = kc * 32 + (lane >> 4) * 8;
        half8 v;
#pragma unroll
        for (int j = 0; j < 8; ++j) v[j] = (_Float16)W[(size_t)(kb + j) * 128 + nn];
        *(half8*)(o + (size_t)slot * 8) = v;
    }
}

// ---------------- privatized histogram: NBLK blocks, packed u16 bins in LDS ----------------------
// part[b][k] (u16 row-major, coalesced flush). Per-block slice ~E/NBLK (=3907) < 65536.
template <int NBINS>
__global__ __launch_bounds__(256) void hist_priv(const int* __restrict__ key,
                                                 unsigned short* __restrict__ part, int E) {
    constexpr int NW = NBINS / 2;
    __shared__ unsigned int h[NW];
    int t = threadIdx.x, b = blockIdx.x;
    for (int i = t; i < NW; i += 256) h[i] = 0;
    __syncthreads();
    int e0 = (int)(((long long)E * b) / NBLK);
    int e1 = (int)(((long long)E * (b + 1)) / NBLK);
    for (int e = e0 + t; e < e1; e += 256) {
        int k = key[e];
        atomicAdd(&h[k >> 1], 1u << ((k & 1) * 16));
    }
    __syncthreads();
    unsigned int* po = (unsigned int*)(part + (size_t)b * NBINS);
    for (int i = t; i < NW; i += 256) po[i] = h[i];
}

// ---------------- column scan over partials: part[b][k] -> exclusive base; cnt[k] = total --------
__global__ __launch_bounds__(256) void colscan(unsigned short* __restrict__ part,
                                               int* __restrict__ cnt, int nbins) {
    int k = blockIdx.x * 256 + threadIdx.x;
    if (k >= nbins) return;
    int run = 0;
#pragma unroll 8
    for (int b = 0; b < NBLK; ++b) {
        size_t idx = (size_t)b * nbins + k;
        int v = part[idx];
        part[idx] = (unsigned short)run;
        run += v;
    }
    cnt[k] = run;
}

// ---------------- scan pass 1 (1024 elems/block) -------------------------------------------------
__global__ __launch_bounds__(256) void scan1(const int* __restrict__ cnt,
                                             int* __restrict__ row,
                                             int* __restrict__ bsum, int N) {
    __shared__ int sd[256];
    int t = threadIdx.x;
    int base = blockIdx.x * 1024 + t * 4;
    int v[4];
#pragma unroll
    for (int j = 0; j < 4; ++j) {
        int idx = base + j;
        v[j] = (idx < N) ? cnt[idx] : 0;
    }
    int tsum = v[0] + v[1] + v[2] + v[3];
    sd[t] = tsum;
    __syncthreads();
    for (int off = 1; off < 256; off <<= 1) {
        int x = (t >= off) ? sd[t - off] : 0;
        __syncthreads();
        sd[t] += x;
        __syncthreads();
    }
    int run = sd[t] - tsum;
#pragma unroll
    for (int j = 0; j < 4; ++j) {
        int idx = base + j;
        if (idx < N) row[idx] = run;
        run += v[j];
    }
    if (t == 255) bsum[blockIdx.x] = sd[255];
}

// ---------------- scan pass 2 --------------------------------------------------------------------
__global__ __launch_bounds__(256) void scan2(int* __restrict__ row,
                                             const int* __restrict__ bsum,
                                             int N, int total) {
    int off = 0;
    for (int b2 = 0; b2 < (int)blockIdx.x; ++b2) off += bsum[b2];
    int t = threadIdx.x;
    int base = blockIdx.x * 1024 + t * 4;
#pragma unroll
    for (int j = 0; j < 4; ++j) {
        int idx = base + j;
        if (idx < N) row[idx] += off;
    }
    if (blockIdx.x == 0 && t == 0) row[N] = total;
}

// ---------------- atomic-free CSR fill: LDS base row + lds fetch_add placement -------------------
template <int NBINS>
__global__ __launch_bounds__(256) void fill_priv(const int* __restrict__ key,
                                                 const int* __restrict__ val,
                                                 const int* __restrict__ rowp,
                                                 const unsigned short* __restrict__ part,
                                                 unsigned short* __restrict__ col, int E) {
    constexpr int NW = NBINS / 2;
    __shared__ unsigned int h[NW];
    int t = threadIdx.x, b = blockIdx.x;
    const unsigned int* pi = (const unsigned int*)(part + (size_t)b * NBINS);
    for (int i = t; i < NW; i += 256) h[i] = pi[i];
    __syncthreads();
    int e0 = (int)(((long long)E * b) / NBLK);
    int e1 = (int)(((long long)E * (b + 1)) / NBLK);
    for (int e = e0 + t; e < e1; e += 256) {
        int k = key[e];
        int v = val[e];
        unsigned int old = atomicAdd(&h[k >> 1], 1u << ((k & 1) * 16));
        int rank = (old >> ((k & 1) * 16)) & 0xffff;
        col[rowp[k] + rank] = (unsigned short)v;
    }
}

// ---------------- fused mean aggregation over ALL nodes ------------------------------------------
// One wave per node. 16 lanes cover one neighbor row (half8 = 16 B/lane), 4 neighbor rows
// in flight per wave instruction, x2 unroll. Shuffle-reduce across the 4 lane groups.
__global__ __launch_bounds__(256) void agg_mean2(const __half* __restrict__ Xg,
                                                 const __half* __restrict__ Xd,
                                                 const int* __restrict__ row,
                                                 const unsigned short* __restrict__ col,
                                                 __half* __restrict__ outd,
                                                 __half* __restrict__ outg) {
    int wid = threadIdx.x >> 6, lane = threadIdx.x & 63;
    int node = blockIdx.x * 4 + wid;
    if (node >= NTOT) return;
    const _Float16* X;
    _Float16* out;
    int nloc;
    if (node < ND) { X = (const _Float16*)Xg; out = (_Float16*)outd; nloc = node; }
    else           { X = (const _Float16*)Xd; out = (_Float16*)outg; nloc = node - ND; }
    int b = row[node], e = row[node + 1];
    int g = lane >> 4, f = lane & 15;
    float acc[8] = {0.f, 0.f, 0.f, 0.f, 0.f, 0.f, 0.f, 0.f};
    int j = b + g;
    for (; j + 4 < e; j += 8) {
        int c0 = col[j], c1 = col[j + 4];
        half8 v0 = *(const half8*)(X + (size_t)c0 * 128 + f * 8);
        half8 v1 = *(const half8*)(X + (size_t)c1 * 128 + f * 8);
#pragma unroll
        for (int k = 0; k < 8; ++k) acc[k] += (float)v0[k] + (float)v1[k];
    }
    if (j < e) {
        int c = col[j];
        half8 v = *(const half8*)(X + (size_t)c * 128 + f * 8);
#pragma unroll
        for (int k = 0; k < 8; ++k) acc[k] += (float)v[k];
    }
#pragma unroll
    for (int k = 0; k < 8; ++k) {
        acc[k] += __shfl_xor(acc[k], 16, 64);
        acc[k] += __shfl_xor(acc[k], 32, 64);
    }
    if (g == 0) {
        int deg = e - b;
        float r = 1.0f / (float)(deg > 0 ? deg : 1);
        half8 o;
#pragma unroll
        for (int k = 0; k < 8; ++k) o[k] = (_Float16)(acc[k] * r);
        *(half8*)(out + (size_t)nloc * 128 + f * 8) = o;
    }
}

// ---------------- MFMA dual GEMM: Y = A1@W1 + A2@W2 + b ------------------------------------------
// 4 waves, 64 rows/block. W pre-swizzled to B-frag layout (L1-resident).
// A-frag: A[m=lane&15][k=quad*8+j]; C/D: col=lane&15, row=quad*4+reg.
__global__ __launch_bounds__(256) void gemm_mfma(const __half* __restrict__ A1,
                                                 const __half* __restrict__ A2,
                                                 const _Float16* __restrict__ Wsw1,
                                                 const _Float16* __restrict__ Wsw2,
                                                 const float* __restrict__ bias,
                                                 float* __restrict__ Yf,
                                                 __half* __restrict__ Yh, int n) {
    int t = threadIdx.x;
    int wave = t >> 6, lane = t & 63;
    int row0 = blockIdx.x * 64 + wave * 16;
    if (row0 >= n) return;
    int m = lane & 15, quad = lane >> 4;
    int arow = row0 + m;
    if (arow >= n) arow = n - 1;
    const _Float16* a1p = (const _Float16*)A1 + (size_t)arow * 128 + quad * 8;
    const _Float16* a2p = (const _Float16*)A2 + (size_t)arow * 128 + quad * 8;
    half8 a1[4], a2[4];
#pragma unroll
    for (int kc = 0; kc < 4; ++kc) {
        a1[kc] = *(const half8*)(a1p + kc * 32);
        a2[kc] = *(const half8*)(a2p + kc * 32);
    }
#pragma unroll
    for (int ntile = 0; ntile < 8; ++ntile) {
        f32x4 acc = {0.f, 0.f, 0.f, 0.f};
#pragma unroll
        for (int kc = 0; kc < 4; ++kc) {
            half8 b1 = *(const half8*)(Wsw1 + (size_t)((ntile * 4 + kc) * 64 + lane) * 8);
            acc = __builtin_amdgcn_mfma_f32_16x16x32_f16(a1[kc], b1, acc, 0, 0, 0);
            half8 b2 = *(const half8*)(Wsw2 + (size_t)((ntile * 4 + kc) * 64 + lane) * 8);
            acc = __builtin_amdgcn_mfma_f32_16x16x32_f16(a2[kc], b2, acc, 0, 0, 0);
        }
        int colx = ntile * 16 + m;
        float bb = bias[colx];
#pragma unroll
        for (int r = 0; r < 4; ++r) {
            int rr = row0 + quad * 4 + r;
            if (rr < n) {
                float v = acc[r] + bb;
                if (Yf) Yf[(size_t)rr * 128 + colx] = v;
                else    Yh[(size_t)rr * 128 + colx] = __float2half(v);
            }
        }
    }
}

extern "C" void kernel_launch(void* const* d_in, const int* in_sizes, int n_in,
                              void* d_out, int out_size, void* d_ws, size_t ws_size,
                              hipStream_t stream) {
    const float* x_d     = (const float*)d_in[0];
    const float* x_g     = (const float*)d_in[1];
    const int*   src     = (const int*)d_in[2];
    const int*   dst     = (const int*)d_in[3];
    const float* w1_dg_l = (const float*)d_in[4];
    const float* b1_dg   = (const float*)d_in[5];
    const float* w1_dg_r = (const float*)d_in[6];
    const float* w1_gd_l = (const float*)d_in[7];
    const float* b1_gd   = (const float*)d_in[8];
    const float* w1_gd_r = (const float*)d_in[9];
    const float* w2_dg_l = (const float*)d_in[10];
    const float* b2_dg   = (const float*)d_in[11];
    const float* w2_dg_r = (const float*)d_in[12];
    const float* w2_gd_l = (const float*)d_in[13];
    const float* b2_gd   = (const float*)d_in[14];
    const float* w2_gd_r = (const float*)d_in[15];
    float* out = (float*)d_out;

    char* ws = (char*)d_ws;
    int*            cnt   = (int*)(ws + OFF_CNT);
    int*            row   = (int*)(ws + OFF_ROW);
    int*            bsum  = (int*)(ws + OFF_BSUM);
    unsigned short* partD = (unsigned short*)(ws + OFF_PARTD);
    unsigned short* partG = (unsigned short*)(ws + OFF_PARTG);
    unsigned short* col   = (unsigned short*)(ws + OFF_COL);
    _Float16*       wsw   = (_Float16*)(ws + OFF_WSW);
    __half*         xd_h  = (__half*)(ws + OFF_XDH);
    __half*         xg_h  = (__half*)(ws + OFF_XGH);
    __half*         md_h  = (__half*)(ws + OFF_MDH);
    __half*         mg_h  = (__half*)(ws + OFF_MGH);
    __half*         d1_h  = (__half*)(ws + OFF_D1H);
    __half*         g1_h  = (__half*)(ws + OFF_G1H);

    const int E = in_sizes[2];              // 1,000,000

    // fp16 conversions + weight swizzle
    cvt2<<<(ND * 32 + NG * 32 + 255) / 256, 256, 0, stream>>>(x_d, x_g, xd_h, xg_h);
    WPtrs wp;
    wp.w[0] = w1_dg_l; wp.w[1] = w1_dg_r; wp.w[2] = w1_gd_l; wp.w[3] = w1_gd_r;
    wp.w[4] = w2_dg_l; wp.w[5] = w2_dg_r; wp.w[6] = w2_gd_l; wp.w[7] = w2_gd_r;
    swz_w<<<8, 256, 0, stream>>>(wp, wsw);

    // ---- CSR build: zero global atomics ----
    hist_priv<ND><<<NBLK, 256, 0, stream>>>(src, partD, E);
    hist_priv<NG><<<NBLK, 256, 0, stream>>>(dst, partG, E);
    colscan<<<(ND + 255) / 256, 256, 0, stream>>>(partD, cnt, ND);
    colscan<<<(NG + 255) / 256, 256, 0, stream>>>(partG, cnt + ND, NG);
    scan1<<<NSCAN_BLOCKS, 256, 0, stream>>>(cnt, row, bsum, NTOT);
    scan2<<<NSCAN_BLOCKS, 256, 0, stream>>>(row, bsum, NTOT, 2 * E);
    fill_priv<ND><<<NBLK, 256, 0, stream>>>(src, dst, row, partD, col, E);
    fill_priv<NG><<<NBLK, 256, 0, stream>>>(dst, src, row + ND, partG, col, E);

    // ---- layer 1 ----
    agg_mean2<<<(NTOT + 3) / 4, 256, 0, stream>>>(xg_h, xd_h, row, col, md_h, mg_h);
    gemm_mfma<<<(ND + 63) / 64, 256, 0, stream>>>(md_h, xd_h, wsw + 2 * 16384, wsw + 3 * 16384,
                                                  b1_gd, (float*)nullptr, d1_h, ND);
    gemm_mfma<<<(NG + 63) / 64, 256, 0, stream>>>(mg_h, xg_h, wsw + 0 * 16384, wsw + 1 * 16384,
                                                  b1_dg, (float*)nullptr, g1_h, NG);

    // ---- layer 2 ----
    agg_mean2<<<(NTOT + 3) / 4, 256, 0, stream>>>(g1_h, d1_h, row, col, md_h, mg_h);
    gemm_mfma<<<(ND + 63) / 64, 256, 0, stream>>>(md_h, d1_h, wsw + 6 * 16384, wsw + 7 * 16384,
                                                  b2_gd, out, (__half*)nullptr, ND);                     // d2
    gemm_mfma<<<(NG + 63) / 64, 256, 0, stream>>>(mg_h, g1_h, wsw + 4 * 16384, wsw + 5 * 16384,
                                                  b2_dg, out + (size_t)ND * 128, (__half*)nullptr, NG);  // g2
}

// Round 7
// 361.289 us; speedup vs baseline: 2.0885x; 1.0383x over previous
//
#include <hip/hip_runtime.h>
#include <hip/hip_fp16.h>

#define ND 25000
#define NG 20000
#define NTOT (ND + NG)      // 45000
#define NSCAN_BLOCKS 44     // ceil(45000/1024)
#define NBLK 256            // histogram / fill privatization blocks (1 per CU)

typedef _Float16 half8 __attribute__((ext_vector_type(8)));
typedef float f32x4 __attribute__((ext_vector_type(4)));
typedef float f32x2 __attribute__((ext_vector_type(2)));

// ---- workspace layout (bytes), 256B-aligned ----
#define OFF_CNT    0ull           // NTOT int (180000)
#define OFF_ROW    180224ull      // NTOT+1 int
#define OFF_BSUM   360448ull      // 64 int
#define OFF_PARTD  360704ull      // NBLK*ND u16 (12,800,000)
#define OFF_PARTG  13160704ull    // NBLK*NG u16 (10,240,000)
#define OFF_COL    23400704ull    // 2*NE u16 (4,000,000)
#define OFF_WSW    27400960ull    // 8*128*128 half (262,144)
#define OFF_XDH    27663360ull    // ND*128 half (6,400,000)
#define OFF_XGH    34063360ull    // NG*128 half (5,120,000)
#define OFF_X8D    39183360ull    // ND*128 fp8 (3,200,000)
#define OFF_X8G    42383360ull    // NG*128 fp8 (2,560,000)
#define OFF_MDH    44943360ull    // ND*128 half (6,400,000)
#define OFF_MGH    51343360ull    // NG*128 half (5,120,000)
#define OFF_D1H    56463360ull    // ND*128 half (6,400,000)   -- contiguous with G1H
#define OFF_G1H    62863360ull    // NG*128 half (5,120,000)
#define OFF_D18    67983360ull    // ND*128 fp8 (3,200,000)    -- contiguous with G18
#define OFF_G18    71183360ull    // NG*128 fp8 (2,560,000)    (end ~73.7 MB)

// ---------------- f32 -> {f16, fp8} convert, both inputs in one dispatch -------------------------
__global__ __launch_bounds__(256) void cvt2(const float* __restrict__ xd,
                                            const float* __restrict__ xg,
                                            __half* __restrict__ yd,
                                            __half* __restrict__ yg,
                                            unsigned char* __restrict__ y8d,
                                            unsigned char* __restrict__ y8g) {
    const int ndq = ND * 32;            // float4 groups in x_disease
    const int tot = ndq + NG * 32;
    int i = blockIdx.x * 256 + threadIdx.x;
    if (i >= tot) return;
    const float* x;
    __half* y;
    unsigned char* y8;
    int idx;
    if (i < ndq) { x = xd; y = yd; y8 = y8d; idx = i; }
    else         { x = xg; y = yg; y8 = y8g; idx = i - ndq; }
    float4 v = ((const float4*)x)[idx];
    ((__half2*)y)[idx * 2 + 0] = __floats2half2_rn(v.x, v.y);
    ((__half2*)y)[idx * 2 + 1] = __floats2half2_rn(v.z, v.w);
    int p8 = __builtin_amdgcn_cvt_pk_fp8_f32(v.x, v.y, 0, false);
    p8 = __builtin_amdgcn_cvt_pk_fp8_f32(v.z, v.w, p8, true);
    ((int*)y8)[idx] = p8;
}

// ---------------- f16 -> fp8 convert (for d1||g1 shadow copy) ------------------------------------
__global__ __launch_bounds__(256) void cvt8(const __half* __restrict__ x,
                                            unsigned char* __restrict__ y, int n4) {
    int i = blockIdx.x * 256 + threadIdx.x;
    if (i >= n4) return;
    float2 a = __half22float2(((const __half2*)x)[i * 2 + 0]);
    float2 b = __half22float2(((const __half2*)x)[i * 2 + 1]);
    int p8 = __builtin_amdgcn_cvt_pk_fp8_f32(a.x, a.y, 0, false);
    p8 = __builtin_amdgcn_cvt_pk_fp8_f32(b.x, b.y, p8, true);
    ((int*)y)[i] = p8;
}

// ---------------- W swizzle: f32 [128][128] row-major -> fp16 MFMA B-fragment layout -------------
struct WPtrs { const float* w[8]; };
__global__ __launch_bounds__(256) void swz_w(WPtrs p, _Float16* __restrict__ dst) {
    int mat = blockIdx.x;            // 0..7
    const float* W = p.w[mat];
    _Float16* o = dst + (size_t)mat * 16384;
    int t = threadIdx.x;
    for (int rep = 0; rep < 8; ++rep) {
        int slot = rep * 256 + t;    // 0..2047
        int lane = slot & 63, grp = slot >> 6;   // grp = ntile*4+kc
        int kc = grp & 3, ntile = grp >> 2;
        int nn = ntile * 16 + (lane & 15);
        int kb = kc * 32 + (lane >> 4) * 8;
        half8 v;
#pragma unroll
        for (int j = 0; j < 8; ++j) v[j] = (_Float16)W[(size_t)(kb + j) * 128 + nn];
        *(half8*)(o + (size_t)slot * 8) = v;
    }
}

// ---------------- privatized histogram: NBLK blocks, packed u16 bins in LDS ----------------------
template <int NBINS>
__global__ __launch_bounds__(256) void hist_priv(const int* __restrict__ key,
                                                 unsigned short* __restrict__ part, int E) {
    constexpr int NW = NBINS / 2;
    __shared__ unsigned int h[NW];
    int t = threadIdx.x, b = blockIdx.x;
    for (int i = t; i < NW; i += 256) h[i] = 0;
    __syncthreads();
    int e0 = (int)(((long long)E * b) / NBLK);
    int e1 = (int)(((long long)E * (b + 1)) / NBLK);
    for (int e = e0 + t; e < e1; e += 256) {
        int k = key[e];
        atomicAdd(&h[k >> 1], 1u << ((k & 1) * 16));
    }
    __syncthreads();
    unsigned int* po = (unsigned int*)(part + (size_t)b * NBINS);
    for (int i = t; i < NW; i += 256) po[i] = h[i];
}

// ---------------- column scan over partials ------------------------------------------------------
__global__ __launch_bounds__(256) void colscan(unsigned short* __restrict__ part,
                                               int* __restrict__ cnt, int nbins) {
    int k = blockIdx.x * 256 + threadIdx.x;
    if (k >= nbins) return;
    int run = 0;
#pragma unroll 8
    for (int b = 0; b < NBLK; ++b) {
        size_t idx = (size_t)b * nbins + k;
        int v = part[idx];
        part[idx] = (unsigned short)run;
        run += v;
    }
    cnt[k] = run;
}

// ---------------- scan pass 1 --------------------------------------------------------------------
__global__ __launch_bounds__(256) void scan1(const int* __restrict__ cnt,
                                             int* __restrict__ row,
                                             int* __restrict__ bsum, int N) {
    __shared__ int sd[256];
    int t = threadIdx.x;
    int base = blockIdx.x * 1024 + t * 4;
    int v[4];
#pragma unroll
    for (int j = 0; j < 4; ++j) {
        int idx = base + j;
        v[j] = (idx < N) ? cnt[idx] : 0;
    }
    int tsum = v[0] + v[1] + v[2] + v[3];
    sd[t] = tsum;
    __syncthreads();
    for (int off = 1; off < 256; off <<= 1) {
        int x = (t >= off) ? sd[t - off] : 0;
        __syncthreads();
        sd[t] += x;
        __syncthreads();
    }
    int run = sd[t] - tsum;
#pragma unroll
    for (int j = 0; j < 4; ++j) {
        int idx = base + j;
        if (idx < N) row[idx] = run;
        run += v[j];
    }
    if (t == 255) bsum[blockIdx.x] = sd[255];
}

// ---------------- scan pass 2 --------------------------------------------------------------------
__global__ __launch_bounds__(256) void scan2(int* __restrict__ row,
                                             const int* __restrict__ bsum,
                                             int N, int total) {
    int off = 0;
    for (int b2 = 0; b2 < (int)blockIdx.x; ++b2) off += bsum[b2];
    int t = threadIdx.x;
    int base = blockIdx.x * 1024 + t * 4;
#pragma unroll
    for (int j = 0; j < 4; ++j) {
        int idx = base + j;
        if (idx < N) row[idx] += off;
    }
    if (blockIdx.x == 0 && t == 0) row[N] = total;
}

// ---------------- atomic-free CSR fill: LDS base row + lds fetch_add placement -------------------
template <int NBINS>
__global__ __launch_bounds__(256) void fill_priv(const int* __restrict__ key,
                                                 const int* __restrict__ val,
                                                 const int* __restrict__ rowp,
                                                 const unsigned short* __restrict__ part,
                                                 unsigned short* __restrict__ col, int E) {
    constexpr int NW = NBINS / 2;
    __shared__ unsigned int h[NW];
    int t = threadIdx.x, b = blockIdx.x;
    const unsigned int* pi = (const unsigned int*)(part + (size_t)b * NBINS);
    for (int i = t; i < NW; i += 256) h[i] = pi[i];
    __syncthreads();
    int e0 = (int)(((long long)E * b) / NBLK);
    int e1 = (int)(((long long)E * (b + 1)) / NBLK);
    for (int e = e0 + t; e < e1; e += 256) {
        int k = key[e];
        int v = val[e];
        unsigned int old = atomicAdd(&h[k >> 1], 1u << ((k & 1) * 16));
        int rank = (old >> ((k & 1) * 16)) & 0xffff;
        col[rowp[k] + rank] = (unsigned short)v;
    }
}

// ---------------- fp8 mean aggregation: one wave per node ----------------------------------------
// 8 lanes cover one neighbor row (16 fp8 = 16 B/lane), 8 rows in flight per wave load, x2 unroll.
// f32 accumulate via v_cvt_pk_f32_fp8; shuffle-reduce across the 8 lane groups; fp16 out.
__global__ __launch_bounds__(256) void agg8(const unsigned char* __restrict__ X8,
                                            const int* __restrict__ rowp,
                                            const unsigned short* __restrict__ col,
                                            __half* __restrict__ out, int n) {
    int wid = threadIdx.x >> 6, lane = threadIdx.x & 63;
    int node = blockIdx.x * 4 + wid;
    if (node >= n) return;
    int b = rowp[node], e = rowp[node + 1];
    int g = lane >> 3, f = lane & 7;     // lane covers elements [f*16, f*16+16)
    float acc[16];
#pragma unroll
    for (int k = 0; k < 16; ++k) acc[k] = 0.f;
    int j = b + g;
    for (; j + 8 < e; j += 16) {
        int c0 = col[j], c1 = col[j + 8];
        int4 w0 = *(const int4*)(X8 + (size_t)c0 * 128 + f * 16);
        int4 w1 = *(const int4*)(X8 + (size_t)c1 * 128 + f * 16);
        const int* wa = (const int*)&w0;
        const int* wb = (const int*)&w1;
#pragma unroll
        for (int q = 0; q < 4; ++q) {
            f32x2 l0 = __builtin_amdgcn_cvt_pk_f32_fp8(wa[q], false);
            f32x2 h0 = __builtin_amdgcn_cvt_pk_f32_fp8(wa[q], true);
            f32x2 l1 = __builtin_amdgcn_cvt_pk_f32_fp8(wb[q], false);
            f32x2 h1 = __builtin_amdgcn_cvt_pk_f32_fp8(wb[q], true);
            acc[q * 4 + 0] += l0[0] + l1[0];
            acc[q * 4 + 1] += l0[1] + l1[1];
            acc[q * 4 + 2] += h0[0] + h1[0];
            acc[q * 4 + 3] += h0[1] + h1[1];
        }
    }
    if (j < e) {
        int c = col[j];
        int4 w = *(const int4*)(X8 + (size_t)c * 128 + f * 16);
        const int* wa = (const int*)&w;
#pragma unroll
        for (int q = 0; q < 4; ++q) {
            f32x2 l = __builtin_amdgcn_cvt_pk_f32_fp8(wa[q], false);
            f32x2 h = __builtin_amdgcn_cvt_pk_f32_fp8(wa[q], true);
            acc[q * 4 + 0] += l[0];
            acc[q * 4 + 1] += l[1];
            acc[q * 4 + 2] += h[0];
            acc[q * 4 + 3] += h[1];
        }
    }
#pragma unroll
    for (int k = 0; k < 16; ++k) {
        acc[k] += __shfl_xor(acc[k], 8, 64);
        acc[k] += __shfl_xor(acc[k], 16, 64);
        acc[k] += __shfl_xor(acc[k], 32, 64);
    }
    if (g == 0) {
        int deg = e - b;
        float r = 1.0f / (float)(deg > 0 ? deg : 1);
        half8 o0, o1;
#pragma unroll
        for (int k = 0; k < 8; ++k) o0[k] = (_Float16)(acc[k] * r);
#pragma unroll
        for (int k = 0; k < 8; ++k) o1[k] = (_Float16)(acc[8 + k] * r);
        _Float16* op = (_Float16*)out + (size_t)node * 128 + f * 16;
        *(half8*)op = o0;
        *(half8*)(op + 8) = o1;
    }
}

// ---------------- MFMA dual GEMM: Y = A1@W1 + A2@W2 + b ------------------------------------------
__global__ __launch_bounds__(256) void gemm_mfma(const __half* __restrict__ A1,
                                                 const __half* __restrict__ A2,
                                                 const _Float16* __restrict__ Wsw1,
                                                 const _Float16* __restrict__ Wsw2,
                                                 const float* __restrict__ bias,
                                                 float* __restrict__ Yf,
                                                 __half* __restrict__ Yh, int n) {
    int t = threadIdx.x;
    int wave = t >> 6, lane = t & 63;
    int row0 = blockIdx.x * 64 + wave * 16;
    if (row0 >= n) return;
    int m = lane & 15, quad = lane >> 4;
    int arow = row0 + m;
    if (arow >= n) arow = n - 1;
    const _Float16* a1p = (const _Float16*)A1 + (size_t)arow * 128 + quad * 8;
    const _Float16* a2p = (const _Float16*)A2 + (size_t)arow * 128 + quad * 8;
    half8 a1[4], a2[4];
#pragma unroll
    for (int kc = 0; kc < 4; ++kc) {
        a1[kc] = *(const half8*)(a1p + kc * 32);
        a2[kc] = *(const half8*)(a2p + kc * 32);
    }
#pragma unroll
    for (int ntile = 0; ntile < 8; ++ntile) {
        f32x4 acc = {0.f, 0.f, 0.f, 0.f};
#pragma unroll
        for (int kc = 0; kc < 4; ++kc) {
            half8 b1 = *(const half8*)(Wsw1 + (size_t)((ntile * 4 + kc) * 64 + lane) * 8);
            acc = __builtin_amdgcn_mfma_f32_16x16x32_f16(a1[kc], b1, acc, 0, 0, 0);
            half8 b2 = *(const half8*)(Wsw2 + (size_t)((ntile * 4 + kc) * 64 + lane) * 8);
            acc = __builtin_amdgcn_mfma_f32_16x16x32_f16(a2[kc], b2, acc, 0, 0, 0);
        }
        int colx = ntile * 16 + m;
        float bb = bias[colx];
#pragma unroll
        for (int r = 0; r < 4; ++r) {
            int rr = row0 + quad * 4 + r;
            if (rr < n) {
                float v = acc[r] + bb;
                if (Yf) Yf[(size_t)rr * 128 + colx] = v;
                else    Yh[(size_t)rr * 128 + colx] = __float2half(v);
            }
        }
    }
}

extern "C" void kernel_launch(void* const* d_in, const int* in_sizes, int n_in,
                              void* d_out, int out_size, void* d_ws, size_t ws_size,
                              hipStream_t stream) {
    const float* x_d     = (const float*)d_in[0];
    const float* x_g     = (const float*)d_in[1];
    const int*   src     = (const int*)d_in[2];
    const int*   dst     = (const int*)d_in[3];
    const float* w1_dg_l = (const float*)d_in[4];
    const float* b1_dg   = (const float*)d_in[5];
    const float* w1_dg_r = (const float*)d_in[6];
    const float* w1_gd_l = (const float*)d_in[7];
    const float* b1_gd   = (const float*)d_in[8];
    const float* w1_gd_r = (const float*)d_in[9];
    const float* w2_dg_l = (const float*)d_in[10];
    const float* b2_dg   = (const float*)d_in[11];
    const float* w2_dg_r = (const float*)d_in[12];
    const float* w2_gd_l = (const float*)d_in[13];
    const float* b2_gd   = (const float*)d_in[14];
    const float* w2_gd_r = (const float*)d_in[15];
    float* out = (float*)d_out;

    char* ws = (char*)d_ws;
    int*            cnt   = (int*)(ws + OFF_CNT);
    int*            row   = (int*)(ws + OFF_ROW);
    int*            bsum  = (int*)(ws + OFF_BSUM);
    unsigned short* partD = (unsigned short*)(ws + OFF_PARTD);
    unsigned short* partG = (unsigned short*)(ws + OFF_PARTG);
    unsigned short* col   = (unsigned short*)(ws + OFF_COL);
    _Float16*       wsw   = (_Float16*)(ws + OFF_WSW);
    __half*         xd_h  = (__half*)(ws + OFF_XDH);
    __half*         xg_h  = (__half*)(ws + OFF_XGH);
    unsigned char*  x8d   = (unsigned char*)(ws + OFF_X8D);
    unsigned char*  x8g   = (unsigned char*)(ws + OFF_X8G);
    __half*         md_h  = (__half*)(ws + OFF_MDH);
    __half*         mg_h  = (__half*)(ws + OFF_MGH);
    __half*         d1_h  = (__half*)(ws + OFF_D1H);
    __half*         g1_h  = (__half*)(ws + OFF_G1H);
    unsigned char*  d1_8  = (unsigned char*)(ws + OFF_D18);

    const int E = in_sizes[2];              // 1,000,000

    // conversions + weight swizzle
    cvt2<<<(ND * 32 + NG * 32 + 255) / 256, 256, 0, stream>>>(x_d, x_g, xd_h, xg_h, x8d, x8g);
    WPtrs wp;
    wp.w[0] = w1_dg_l; wp.w[1] = w1_dg_r; wp.w[2] = w1_gd_l; wp.w[3] = w1_gd_r;
    wp.w[4] = w2_dg_l; wp.w[5] = w2_dg_r; wp.w[6] = w2_gd_l; wp.w[7] = w2_gd_r;
    swz_w<<<8, 256, 0, stream>>>(wp, wsw);

    // ---- CSR build: zero global atomics ----
    hist_priv<ND><<<NBLK, 256, 0, stream>>>(src, partD, E);
    hist_priv<NG><<<NBLK, 256, 0, stream>>>(dst, partG, E);
    colscan<<<(ND + 255) / 256, 256, 0, stream>>>(partD, cnt, ND);
    colscan<<<(NG + 255) / 256, 256, 0, stream>>>(partG, cnt + ND, NG);
    scan1<<<NSCAN_BLOCKS, 256, 0, stream>>>(cnt, row, bsum, NTOT);
    scan2<<<NSCAN_BLOCKS, 256, 0, stream>>>(row, bsum, NTOT, 2 * E);
    fill_priv<ND><<<NBLK, 256, 0, stream>>>(src, dst, row, partD, col, E);
    fill_priv<NG><<<NBLK, 256, 0, stream>>>(dst, src, row + ND, partG, col, E);

    // ---- layer 1 (agg split per type: fp8 source fits per-XCD L2) ----
    agg8<<<(ND + 3) / 4, 256, 0, stream>>>(x8g, row, col, md_h, ND);        // disease <- mean(genes)
    agg8<<<(NG + 3) / 4, 256, 0, stream>>>(x8d, row + ND, col, mg_h, NG);   // gene <- mean(diseases)
    gemm_mfma<<<(ND + 63) / 64, 256, 0, stream>>>(md_h, xd_h, wsw + 2 * 16384, wsw + 3 * 16384,
                                                  b1_gd, (float*)nullptr, d1_h, ND);
    gemm_mfma<<<(NG + 63) / 64, 256, 0, stream>>>(mg_h, xg_h, wsw + 0 * 16384, wsw + 1 * 16384,
                                                  b1_dg, (float*)nullptr, g1_h, NG);
    // fp8 shadow of d1||g1 (contiguous) for layer-2 aggregation
    cvt8<<<(NTOT * 32 + 255) / 256, 256, 0, stream>>>(d1_h, d1_8, NTOT * 32);

    // ---- layer 2 ----
    agg8<<<(ND + 3) / 4, 256, 0, stream>>>(d1_8 + ND * 128, row, col, md_h, ND);   // disease <- mean(g1)
    agg8<<<(NG + 3) / 4, 256, 0, stream>>>(d1_8, row + ND, col, mg_h, NG);         // gene <- mean(d1)
    gemm_mfma<<<(ND + 63) / 64, 256, 0, stream>>>(md_h, d1_h, wsw + 6 * 16384, wsw + 7 * 16384,
                                                  b2_gd, out, (__half*)nullptr, ND);                     // d2
    gemm_mfma<<<(NG + 63) / 64, 256, 0, stream>>>(mg_h, g1_h, wsw + 4 * 16384, wsw + 5 * 16384,
                                                  b2_dg, out + (size_t)ND * 128, (__half*)nullptr, NG);  // g2
}

// Round 8
// 255.687 us; speedup vs baseline: 2.9511x; 1.4130x over previous
//
#include <hip/hip_runtime.h>
#include <hip/hip_fp16.h>

#define ND 25000
#define NG 20000
#define NTOT (ND + NG)      // 45000
#define NSCAN_BLOCKS 44     // ceil(45000/1024)
#define NBLK 128            // privatization slices PER NODE TYPE (2*NBLK blocks per dispatch)

typedef _Float16 half8 __attribute__((ext_vector_type(8)));
typedef float f32x4 __attribute__((ext_vector_type(4)));
typedef float f32x2 __attribute__((ext_vector_type(2)));

// ---- workspace layout (bytes), 256B-aligned ----
#define OFF_CNT    0ull           // NTOT int (180000)
#define OFF_ROW    180224ull      // NTOT+1 int
#define OFF_BSUM   360448ull      // 64 int
#define OFF_PARTD  360704ull      // NBLK*ND u16 (6,400,000)
#define OFF_PARTG  6760704ull     // NBLK*NG u16 (5,120,000)
#define OFF_COL    11880704ull    // 2*NE u16 (4,000,000)
#define OFF_WSW    15880704ull    // 8*128*128 half (262,144)
#define OFF_XDH    16142848ull    // ND*128 half (6,400,000)
#define OFF_XGH    22542848ull    // NG*128 half (5,120,000)
#define OFF_X8D    27662848ull    // ND*128 fp8 (3,200,000)
#define OFF_X8G    30862848ull    // NG*128 fp8 (2,560,000)
#define OFF_MDH    33422848ull    // ND*128 half (6,400,000)
#define OFF_MGH    39822848ull    // NG*128 half (5,120,000)
#define OFF_D1H    44942848ull    // ND*128 half (6,400,000)
#define OFF_G1H    51342848ull    // NG*128 half (5,120,000)
#define OFF_D18    56462848ull    // ND*128 fp8 (3,200,000)
#define OFF_G18    59662848ull    // NG*128 fp8 (2,560,000)   (end ~62.2 MB)

struct WPtrs { const float* w[8]; };

// ---------------- prep: blocks 0..7 = weight swizzle; rest = f32 -> {f16,fp8} convert ------------
// W swizzle: slot=(ntile*4+kc)*64+lane; elem j = W[kc*32+(lane>>4)*8+j][ntile*16+(lane&15)]
__global__ __launch_bounds__(256) void prep(const float* __restrict__ xd,
                                            const float* __restrict__ xg,
                                            __half* __restrict__ yd,
                                            __half* __restrict__ yg,
                                            unsigned char* __restrict__ y8d,
                                            unsigned char* __restrict__ y8g,
                                            WPtrs p, _Float16* __restrict__ wsw) {
    int t = threadIdx.x;
    if (blockIdx.x < 8) {
        int mat = blockIdx.x;
        const float* W = p.w[mat];
        _Float16* o = wsw + (size_t)mat * 16384;
        for (int rep = 0; rep < 8; ++rep) {
            int slot = rep * 256 + t;
            int lane = slot & 63, grp = slot >> 6;
            int kc = grp & 3, ntile = grp >> 2;
            int nn = ntile * 16 + (lane & 15);
            int kb = kc * 32 + (lane >> 4) * 8;
            half8 v;
#pragma unroll
            for (int j = 0; j < 8; ++j) v[j] = (_Float16)W[(size_t)(kb + j) * 128 + nn];
            *(half8*)(o + (size_t)slot * 8) = v;
        }
        return;
    }
    const int ndq = ND * 32;
    const int tot = ndq + NG * 32;
    int i = (blockIdx.x - 8) * 256 + t;
    if (i >= tot) return;
    const float* x;
    __half* y;
    unsigned char* y8;
    int idx;
    if (i < ndq) { x = xd; y = yd; y8 = y8d; idx = i; }
    else         { x = xg; y = yg; y8 = y8g; idx = i - ndq; }
    float4 v = ((const float4*)x)[idx];
    ((__half2*)y)[idx * 2 + 0] = __floats2half2_rn(v.x, v.y);
    ((__half2*)y)[idx * 2 + 1] = __floats2half2_rn(v.z, v.w);
    int p8 = __builtin_amdgcn_cvt_pk_fp8_f32(v.x, v.y, 0, false);
    p8 = __builtin_amdgcn_cvt_pk_fp8_f32(v.z, v.w, p8, true);
    ((int*)y8)[idx] = p8;
}

// ---------------- merged privatized histogram: blocks [0,NBLK)=disease, [NBLK,2NBLK)=gene --------
__global__ __launch_bounds__(256) void hist2(const int* __restrict__ src,
                                             const int* __restrict__ dst,
                                             unsigned short* __restrict__ partD,
                                             unsigned short* __restrict__ partG, int E) {
    __shared__ unsigned int h[12544];     // 50 KB, covers ND/2=12500
    int t = threadIdx.x, b = blockIdx.x;
    bool isD = b < NBLK;
    int bb = isD ? b : b - NBLK;
    const int* key = isD ? src : dst;
    int nw = isD ? (ND / 2) : (NG / 2);
    for (int i = t; i < nw; i += 256) h[i] = 0;
    __syncthreads();
    int e0 = (int)(((long long)E * bb) / NBLK);
    int e1 = (int)(((long long)E * (bb + 1)) / NBLK);
    for (int e = e0 + t; e < e1; e += 256) {
        int k = key[e];
        atomicAdd(&h[k >> 1], 1u << ((k & 1) * 16));
    }
    __syncthreads();
    unsigned int* po = (unsigned int*)((isD ? partD : partG) + (size_t)bb * (isD ? ND : NG));
    for (int i = t; i < nw; i += 256) po[i] = h[i];
}

// ---------------- merged column scan over partials -----------------------------------------------
__global__ __launch_bounds__(256) void colscan2(unsigned short* __restrict__ partD,
                                                unsigned short* __restrict__ partG,
                                                int* __restrict__ cnt) {
    int k = blockIdx.x * 256 + threadIdx.x;
    if (k >= NTOT) return;
    unsigned short* part;
    int nb, kk;
    if (k < ND) { part = partD; nb = ND; kk = k; }
    else        { part = partG; nb = NG; kk = k - ND; }
    int run = 0;
#pragma unroll 8
    for (int b = 0; b < NBLK; ++b) {
        size_t idx = (size_t)b * nb + kk;
        int v = part[idx];
        part[idx] = (unsigned short)run;
        run += v;
    }
    cnt[k] = run;
}

// ---------------- scan pass 1 --------------------------------------------------------------------
__global__ __launch_bounds__(256) void scan1(const int* __restrict__ cnt,
                                             int* __restrict__ row,
                                             int* __restrict__ bsum, int N) {
    __shared__ int sd[256];
    int t = threadIdx.x;
    int base = blockIdx.x * 1024 + t * 4;
    int v[4];
#pragma unroll
    for (int j = 0; j < 4; ++j) {
        int idx = base + j;
        v[j] = (idx < N) ? cnt[idx] : 0;
    }
    int tsum = v[0] + v[1] + v[2] + v[3];
    sd[t] = tsum;
    __syncthreads();
    for (int off = 1; off < 256; off <<= 1) {
        int x = (t >= off) ? sd[t - off] : 0;
        __syncthreads();
        sd[t] += x;
        __syncthreads();
    }
    int run = sd[t] - tsum;
#pragma unroll
    for (int j = 0; j < 4; ++j) {
        int idx = base + j;
        if (idx < N) row[idx] = run;
        run += v[j];
    }
    if (t == 255) bsum[blockIdx.x] = sd[255];
}

// ---------------- scan pass 2 --------------------------------------------------------------------
__global__ __launch_bounds__(256) void scan2(int* __restrict__ row,
                                             const int* __restrict__ bsum,
                                             int N, int total) {
    int off = 0;
    for (int b2 = 0; b2 < (int)blockIdx.x; ++b2) off += bsum[b2];
    int t = threadIdx.x;
    int base = blockIdx.x * 1024 + t * 4;
#pragma unroll
    for (int j = 0; j < 4; ++j) {
        int idx = base + j;
        if (idx < N) row[idx] += off;
    }
    if (blockIdx.x == 0 && t == 0) row[N] = total;
}

// ---------------- merged atomic-free CSR fill ----------------------------------------------------
__global__ __launch_bounds__(256) void fill2(const int* __restrict__ src,
                                             const int* __restrict__ dst,
                                             const int* __restrict__ row,
                                             const unsigned short* __restrict__ partD,
                                             const unsigned short* __restrict__ partG,
                                             unsigned short* __restrict__ col, int E) {
    __shared__ unsigned int h[12544];
    int t = threadIdx.x, b = blockIdx.x;
    bool isD = b < NBLK;
    int bb = isD ? b : b - NBLK;
    const int* key = isD ? src : dst;
    const int* val = isD ? dst : src;
    const int* rowp = isD ? row : row + ND;
    int nw = isD ? (ND / 2) : (NG / 2);
    const unsigned int* pi =
        (const unsigned int*)((isD ? partD : partG) + (size_t)bb * (isD ? ND : NG));
    for (int i = t; i < nw; i += 256) h[i] = pi[i];
    __syncthreads();
    int e0 = (int)(((long long)E * bb) / NBLK);
    int e1 = (int)(((long long)E * (bb + 1)) / NBLK);
    for (int e = e0 + t; e < e1; e += 256) {
        int k = key[e];
        int v = val[e];
        unsigned int old = atomicAdd(&h[k >> 1], 1u << ((k & 1) * 16));
        int rank = (old >> ((k & 1) * 16)) & 0xffff;
        col[rowp[k] + rank] = (unsigned short)v;
    }
}

// ---------------- merged fp8 mean aggregation over ALL nodes -------------------------------------
// One wave per node; 8 lanes per neighbor row (16 B/lane), 8 rows per wave load, x2 unroll.
__global__ __launch_bounds__(256) void agg8m(const unsigned char* __restrict__ Xg,
                                             const unsigned char* __restrict__ Xd,
                                             const int* __restrict__ row,
                                             const unsigned short* __restrict__ col,
                                             __half* __restrict__ outd,
                                             __half* __restrict__ outg) {
    int wid = threadIdx.x >> 6, lane = threadIdx.x & 63;
    int node = blockIdx.x * 4 + wid;
    if (node >= NTOT) return;
    const unsigned char* X;
    _Float16* out;
    int nloc;
    if (node < ND) { X = Xg; out = (_Float16*)outd; nloc = node; }
    else           { X = Xd; out = (_Float16*)outg; nloc = node - ND; }
    int b = row[node], e = row[node + 1];
    int g = lane >> 3, f = lane & 7;
    float acc[16];
#pragma unroll
    for (int k = 0; k < 16; ++k) acc[k] = 0.f;
    int j = b + g;
    for (; j + 8 < e; j += 16) {
        int c0 = col[j], c1 = col[j + 8];
        int4 w0 = *(const int4*)(X + (size_t)c0 * 128 + f * 16);
        int4 w1 = *(const int4*)(X + (size_t)c1 * 128 + f * 16);
        const int* wa = (const int*)&w0;
        const int* wb = (const int*)&w1;
#pragma unroll
        for (int q = 0; q < 4; ++q) {
            f32x2 l0 = __builtin_amdgcn_cvt_pk_f32_fp8(wa[q], false);
            f32x2 h0 = __builtin_amdgcn_cvt_pk_f32_fp8(wa[q], true);
            f32x2 l1 = __builtin_amdgcn_cvt_pk_f32_fp8(wb[q], false);
            f32x2 h1 = __builtin_amdgcn_cvt_pk_f32_fp8(wb[q], true);
            acc[q * 4 + 0] += l0[0] + l1[0];
            acc[q * 4 + 1] += l0[1] + l1[1];
            acc[q * 4 + 2] += h0[0] + h1[0];
            acc[q * 4 + 3] += h0[1] + h1[1];
        }
    }
    if (j < e) {
        int c = col[j];
        int4 w = *(const int4*)(X + (size_t)c * 128 + f * 16);
        const int* wa = (const int*)&w;
#pragma unroll
        for (int q = 0; q < 4; ++q) {
            f32x2 l = __builtin_amdgcn_cvt_pk_f32_fp8(wa[q], false);
            f32x2 h = __builtin_amdgcn_cvt_pk_f32_fp8(wa[q], true);
            acc[q * 4 + 0] += l[0];
            acc[q * 4 + 1] += l[1];
            acc[q * 4 + 2] += h[0];
            acc[q * 4 + 3] += h[1];
        }
    }
#pragma unroll
    for (int k = 0; k < 16; ++k) {
        acc[k] += __shfl_xor(acc[k], 8, 64);
        acc[k] += __shfl_xor(acc[k], 16, 64);
        acc[k] += __shfl_xor(acc[k], 32, 64);
    }
    if (g == 0) {
        int deg = e - b;
        float r = 1.0f / (float)(deg > 0 ? deg : 1);
        half8 o0, o1;
#pragma unroll
        for (int k = 0; k < 8; ++k) o0[k] = (_Float16)(acc[k] * r);
#pragma unroll
        for (int k = 0; k < 8; ++k) o1[k] = (_Float16)(acc[8 + k] * r);
        _Float16* op = out + (size_t)nloc * 128 + f * 16;
        *(half8*)op = o0;
        *(half8*)(op + 8) = o1;
    }
}

// ---------------- merged MFMA dual GEMM (both node types in one dispatch) ------------------------
// Per sub-problem: Y = A1@W1 + A2@W2 + b. Layer1: Yh + fp8 shadow Y8; Layer2: f32 Yf.
struct GemmDual {
    const __half *A1d, *A2d, *A1g, *A2g;
    const _Float16 *W1d, *W2d, *W1g, *W2g;
    const float *biasd, *biasg;
    float *Yfd, *Yfg;
    __half *Yhd, *Yhg;
    unsigned char *Y8d, *Y8g;
};
__global__ __launch_bounds__(256) void gemm2(GemmDual p, int nblkD) {
    int bx = blockIdx.x;
    const __half *A1, *A2;
    const _Float16 *W1, *W2;
    const float* bias;
    float* Yf;
    __half* Yh;
    unsigned char* Y8;
    int n, b0;
    if (bx < nblkD) {
        A1 = p.A1d; A2 = p.A2d; W1 = p.W1d; W2 = p.W2d; bias = p.biasd;
        Yf = p.Yfd; Yh = p.Yhd; Y8 = p.Y8d; n = ND; b0 = bx;
    } else {
        A1 = p.A1g; A2 = p.A2g; W1 = p.W1g; W2 = p.W2g; bias = p.biasg;
        Yf = p.Yfg; Yh = p.Yhg; Y8 = p.Y8g; n = NG; b0 = bx - nblkD;
    }
    int t = threadIdx.x;
    int wave = t >> 6, lane = t & 63;
    int row0 = b0 * 64 + wave * 16;
    if (row0 >= n) return;
    int m = lane & 15, quad = lane >> 4;
    int arow = row0 + m;
    if (arow >= n) arow = n - 1;
    const _Float16* a1p = (const _Float16*)A1 + (size_t)arow * 128 + quad * 8;
    const _Float16* a2p = (const _Float16*)A2 + (size_t)arow * 128 + quad * 8;
    half8 a1[4], a2[4];
#pragma unroll
    for (int kc = 0; kc < 4; ++kc) {
        a1[kc] = *(const half8*)(a1p + kc * 32);
        a2[kc] = *(const half8*)(a2p + kc * 32);
    }
#pragma unroll
    for (int ntile = 0; ntile < 8; ++ntile) {
        f32x4 acc = {0.f, 0.f, 0.f, 0.f};
#pragma unroll
        for (int kc = 0; kc < 4; ++kc) {
            half8 b1 = *(const half8*)(W1 + (size_t)((ntile * 4 + kc) * 64 + lane) * 8);
            acc = __builtin_amdgcn_mfma_f32_16x16x32_f16(a1[kc], b1, acc, 0, 0, 0);
            half8 b2 = *(const half8*)(W2 + (size_t)((ntile * 4 + kc) * 64 + lane) * 8);
            acc = __builtin_amdgcn_mfma_f32_16x16x32_f16(a2[kc], b2, acc, 0, 0, 0);
        }
        int colx = ntile * 16 + m;
        float bb = bias[colx];
#pragma unroll
        for (int r = 0; r < 4; ++r) {
            int rr = row0 + quad * 4 + r;
            if (rr < n) {
                float v = acc[r] + bb;
                if (Yf) {
                    Yf[(size_t)rr * 128 + colx] = v;
                } else {
                    Yh[(size_t)rr * 128 + colx] = __float2half(v);
                    int p8 = __builtin_amdgcn_cvt_pk_fp8_f32(v, v, 0, false);
                    Y8[(size_t)rr * 128 + colx] = (unsigned char)(p8 & 0xff);
                }
            }
        }
    }
}

extern "C" void kernel_launch(void* const* d_in, const int* in_sizes, int n_in,
                              void* d_out, int out_size, void* d_ws, size_t ws_size,
                              hipStream_t stream) {
    const float* x_d     = (const float*)d_in[0];
    const float* x_g     = (const float*)d_in[1];
    const int*   src     = (const int*)d_in[2];
    const int*   dst     = (const int*)d_in[3];
    const float* w1_dg_l = (const float*)d_in[4];
    const float* b1_dg   = (const float*)d_in[5];
    const float* w1_dg_r = (const float*)d_in[6];
    const float* w1_gd_l = (const float*)d_in[7];
    const float* b1_gd   = (const float*)d_in[8];
    const float* w1_gd_r = (const float*)d_in[9];
    const float* w2_dg_l = (const float*)d_in[10];
    const float* b2_dg   = (const float*)d_in[11];
    const float* w2_dg_r = (const float*)d_in[12];
    const float* w2_gd_l = (const float*)d_in[13];
    const float* b2_gd   = (const float*)d_in[14];
    const float* w2_gd_r = (const float*)d_in[15];
    float* out = (float*)d_out;

    char* ws = (char*)d_ws;
    int*            cnt   = (int*)(ws + OFF_CNT);
    int*            row   = (int*)(ws + OFF_ROW);
    int*            bsum  = (int*)(ws + OFF_BSUM);
    unsigned short* partD = (unsigned short*)(ws + OFF_PARTD);
    unsigned short* partG = (unsigned short*)(ws + OFF_PARTG);
    unsigned short* col   = (unsigned short*)(ws + OFF_COL);
    _Float16*       wsw   = (_Float16*)(ws + OFF_WSW);
    __half*         xd_h  = (__half*)(ws + OFF_XDH);
    __half*         xg_h  = (__half*)(ws + OFF_XGH);
    unsigned char*  x8d   = (unsigned char*)(ws + OFF_X8D);
    unsigned char*  x8g   = (unsigned char*)(ws + OFF_X8G);
    __half*         md_h  = (__half*)(ws + OFF_MDH);
    __half*         mg_h  = (__half*)(ws + OFF_MGH);
    __half*         d1_h  = (__half*)(ws + OFF_D1H);
    __half*         g1_h  = (__half*)(ws + OFF_G1H);
    unsigned char*  d1_8  = (unsigned char*)(ws + OFF_D18);
    unsigned char*  g1_8  = (unsigned char*)(ws + OFF_G18);

    const int E = in_sizes[2];              // 1,000,000
    const int nblkD = (ND + 63) / 64;       // 391
    const int nblkG = (NG + 63) / 64;       // 313

    // 1. prep: weight swizzle (8 blocks) + f32->{f16,fp8} convert
    WPtrs wp;
    wp.w[0] = w1_dg_l; wp.w[1] = w1_dg_r; wp.w[2] = w1_gd_l; wp.w[3] = w1_gd_r;
    wp.w[4] = w2_dg_l; wp.w[5] = w2_dg_r; wp.w[6] = w2_gd_l; wp.w[7] = w2_gd_r;
    prep<<<8 + (NTOT * 32 + 255) / 256, 256, 0, stream>>>(x_d, x_g, xd_h, xg_h, x8d, x8g, wp, wsw);

    // 2-6. CSR build: zero global atomics
    hist2<<<2 * NBLK, 256, 0, stream>>>(src, dst, partD, partG, E);
    colscan2<<<(NTOT + 255) / 256, 256, 0, stream>>>(partD, partG, cnt);
    scan1<<<NSCAN_BLOCKS, 256, 0, stream>>>(cnt, row, bsum, NTOT);
    scan2<<<NSCAN_BLOCKS, 256, 0, stream>>>(row, bsum, NTOT, 2 * E);
    fill2<<<2 * NBLK, 256, 0, stream>>>(src, dst, row, partD, partG, col, E);

    // 7-8. layer 1
    agg8m<<<(NTOT + 3) / 4, 256, 0, stream>>>(x8g, x8d, row, col, md_h, mg_h);
    GemmDual g1p;
    g1p.A1d = md_h; g1p.A2d = xd_h; g1p.W1d = wsw + 2 * 16384; g1p.W2d = wsw + 3 * 16384;
    g1p.biasd = b1_gd; g1p.Yfd = nullptr; g1p.Yhd = d1_h; g1p.Y8d = d1_8;
    g1p.A1g = mg_h; g1p.A2g = xg_h; g1p.W1g = wsw + 0 * 16384; g1p.W2g = wsw + 1 * 16384;
    g1p.biasg = b1_dg; g1p.Yfg = nullptr; g1p.Yhg = g1_h; g1p.Y8g = g1_8;
    gemm2<<<nblkD + nblkG, 256, 0, stream>>>(g1p, nblkD);

    // 9-10. layer 2
    agg8m<<<(NTOT + 3) / 4, 256, 0, stream>>>(g1_8, d1_8, row, col, md_h, mg_h);
    GemmDual g2p;
    g2p.A1d = md_h; g2p.A2d = d1_h; g2p.W1d = wsw + 6 * 16384; g2p.W2d = wsw + 7 * 16384;
    g2p.biasd = b2_gd; g2p.Yfd = out; g2p.Yhd = nullptr; g2p.Y8d = nullptr;
    g2p.A1g = mg_h; g2p.A2g = g1_h; g2p.W1g = wsw + 4 * 16384; g2p.W2g = wsw + 5 * 16384;
    g2p.biasg = b2_dg; g2p.Yfg = out + (size_t)ND * 128; g2p.Yhg = nullptr; g2p.Y8g = nullptr;
    gemm2<<<nblkD + nblkG, 256, 0, stream>>>(g2p, nblkD);
}